// Round 1
// baseline (2085.453 us; speedup 1.0000x reference)
//
#include <hip/hip_runtime.h>
#include <math.h>

#define NNODES 8192

// ---------------------------------------------------------------------------
// Generic tiled f32 GEMM: C[MxN] = A[MxK] @ B[KxN], all row-major.
// 64x64 C-tile per 256-thread block, BK=16, 4x4 micro-tile per thread.
// ---------------------------------------------------------------------------
__global__ __launch_bounds__(256) void gemm64(const float* __restrict__ A,
                                              const float* __restrict__ B,
                                              float* __restrict__ C,
                                              int M, int N, int K)
{
    __shared__ float sA[16][68];   // sA[k][m], pad 68 keeps 16B alignment + 2-way max
    __shared__ float sB[16][68];   // sB[k][n]

    const int tid = threadIdx.x;
    const int tx = tid & 15, ty = tid >> 4;
    const int bm = blockIdx.x * 64, bn = blockIdx.y * 64;

    float acc[4][4] = {};

    for (int k0 = 0; k0 < K; k0 += 16) {
        // A tile 64x16 -> sA[k][m]
        for (int l = tid; l < 64 * 16; l += 256) {
            int m = l >> 4, k = l & 15;
            sA[k][m] = A[(size_t)(bm + m) * K + k0 + k];
        }
        // B tile 16x64 -> sB[k][n]  (coalesced along n)
        for (int l = tid; l < 16 * 64; l += 256) {
            int k = l >> 6, n = l & 63;
            sB[k][n] = B[(size_t)(k0 + k) * N + bn + n];
        }
        __syncthreads();
#pragma unroll
        for (int k = 0; k < 16; ++k) {
            float a[4], b[4];
#pragma unroll
            for (int i = 0; i < 4; ++i) a[i] = sA[k][ty * 4 + i];
#pragma unroll
            for (int j = 0; j < 4; ++j) b[j] = sB[k][tx * 4 + j];
#pragma unroll
            for (int i = 0; i < 4; ++i)
#pragma unroll
                for (int j = 0; j < 4; ++j) acc[i][j] += a[i] * b[j];
        }
        __syncthreads();
    }

#pragma unroll
    for (int i = 0; i < 4; ++i) {
        float4 v = make_float4(acc[i][0], acc[i][1], acc[i][2], acc[i][3]);
        *(float4*)&C[(size_t)(bm + ty * 4 + i) * N + bn + tx * 4] = v;
    }
}

// ---------------------------------------------------------------------------
// s = h @ a_self, n = h @ a_neigh  (one wave per row)
// ---------------------------------------------------------------------------
template <int D>
__global__ __launch_bounds__(256) void sn_kernel(const float* __restrict__ h,
                                                 const float* __restrict__ a_s,
                                                 const float* __restrict__ a_n,
                                                 float* __restrict__ sv,
                                                 float* __restrict__ nv)
{
    const int row = (blockIdx.x * 256 + threadIdx.x) >> 6;
    const int lane = threadIdx.x & 63;
    if (row >= NNODES) return;
    const float* hr = h + (size_t)row * D;
    float a0 = 0.f, a1 = 0.f;
#pragma unroll
    for (int k = lane; k < D; k += 64) {
        float hv = hr[k];
        a0 += hv * a_s[k];
        a1 += hv * a_n[k];
    }
#pragma unroll
    for (int o = 32; o; o >>= 1) {
        a0 += __shfl_down(a0, o);
        a1 += __shfl_down(a1, o);
    }
    if (lane == 0) { sv[row] = a0; nv[row] = a1; }
}

// ---------------------------------------------------------------------------
// Fused masked-softmax attention row:  out[i,:] = elu( softmax_j(e_ij) @ h )
// e_ij = leakyrelu((s_i + n_j) * M_ij) where adj_ij > 0, else -9e15.
// One 256-thread block per row. Exploits ~5% sparsity: compact nonzero cols
// (deterministic order), gather only those h rows.
// ---------------------------------------------------------------------------
template <int D>
__global__ __launch_bounds__(256) void attn_kernel(const float* __restrict__ adj,
                                                   const float* __restrict__ Mm,
                                                   const float* __restrict__ sv,
                                                   const float* __restrict__ nv,
                                                   const float* __restrict__ h,
                                                   float* __restrict__ out)
{
    constexpr int NT = 256;
    constexpr int CAP = 2048;          // expected nnz/row ~410; fallback if exceeded
    __shared__ float pbuf[NNODES];     // 32 KB: masked scores, then probabilities
    __shared__ int   idxb[CAP];        // 8 KB: compacted nonzero columns
    __shared__ int   cnts[NT];
    __shared__ float reds[4];
    __shared__ float fbcast;
    __shared__ int   totc;

    const int tid = threadIdx.x;
    const int i = blockIdx.x;
    const size_t rowoff = (size_t)i * NNODES;
    const float si = sv[i];

    // ---- phase 1: masked leaky-relu scores + row max ----
    float lmax = -3.0e38f;
    for (int j = tid; j < NNODES; j += NT) {
        float a = adj[rowoff + j];
        float val = -9.0e15f;
        if (a > 0.f) {
            float e = (si + nv[j]) * Mm[rowoff + j];
            val = e > 0.f ? e : 0.2f * e;
            lmax = fmaxf(lmax, val);
        }
        pbuf[j] = val;
    }
#pragma unroll
    for (int o = 32; o; o >>= 1) lmax = fmaxf(lmax, __shfl_down(lmax, o));
    if ((tid & 63) == 0) reds[tid >> 6] = lmax;
    __syncthreads();
    if (tid == 0) fbcast = fmaxf(fmaxf(reds[0], reds[1]), fmaxf(reds[2], reds[3]));
    __syncthreads();
    const float m = fbcast;

    // ---- phase 2: exp + row sum + per-thread nnz count ----
    float lsum = 0.f;
    int myc = 0;
    for (int j = tid; j < NNODES; j += NT) {
        float v = pbuf[j];
        float p = (v > -8.9e15f) ? expf(v - m) : 0.f;
        pbuf[j] = p;
        lsum += p;
        if (p > 0.f) myc++;
    }
#pragma unroll
    for (int o = 32; o; o >>= 1) lsum += __shfl_down(lsum, o);
    if ((tid & 63) == 0) reds[tid >> 6] = lsum;
    cnts[tid] = myc;
    __syncthreads();
    if (tid == 0) {
        fbcast = reds[0] + reds[1] + reds[2] + reds[3];
        int run = 0;
        for (int t = 0; t < NT; ++t) { int c = cnts[t]; cnts[t] = run; run += c; }
        totc = run;
    }
    __syncthreads();
    const float inv = 1.0f / fbcast;
    const int nnz = totc;

    // ---- phase 3: deterministic compaction of nonzero columns ----
    if (nnz <= CAP) {
        int off = cnts[tid];
        for (int j = tid; j < NNODES; j += NT)
            if (pbuf[j] > 0.f) idxb[off++] = j;
    }
    __syncthreads();

    // ---- phase 4: sparse PV gather + scale + ELU ----
    if constexpr (D == 512) {
        const int c = tid;
        float acc0 = 0.f, acc1 = 0.f;
        if (nnz <= CAP) {
#pragma unroll 4
            for (int t = 0; t < nnz; ++t) {
                int j = idxb[t];
                float pj = pbuf[j];
                const float* hr = h + (size_t)j * 512;
                acc0 += pj * hr[c];
                acc1 += pj * hr[c + 256];
            }
        } else {
            for (int j = 0; j < NNODES; ++j) {
                float pj = pbuf[j];
                if (pj > 0.f) {
                    const float* hr = h + (size_t)j * 512;
                    acc0 += pj * hr[c];
                    acc1 += pj * hr[c + 256];
                }
            }
        }
        float r0 = acc0 * inv, r1 = acc1 * inv;
        out[(size_t)i * 512 + c]       = r0 > 0.f ? r0 : expm1f(r0);
        out[(size_t)i * 512 + c + 256] = r1 > 0.f ? r1 : expm1f(r1);
    } else {  // D == 128: two thread-groups split the j-range
        const int half = tid >> 7;
        const int c = tid & 127;
        float acc = 0.f;
        if (nnz <= CAP) {
#pragma unroll 4
            for (int t = half; t < nnz; t += 2) {
                int j = idxb[t];
                acc += pbuf[j] * h[(size_t)j * 128 + c];
            }
        } else {
            for (int j = half; j < NNODES; j += 2) {
                float pj = pbuf[j];
                if (pj > 0.f) acc += pj * h[(size_t)j * 128 + c];
            }
        }
        __syncthreads();           // everyone done reading pbuf
        pbuf[tid] = acc;
        __syncthreads();
        if (tid < 128) {
            float r = (pbuf[tid] + pbuf[tid + 128]) * inv;
            out[(size_t)i * 128 + tid] = r > 0.f ? r : expm1f(r);
        }
    }
}

// ---------------------------------------------------------------------------
// z = h / max(||h||_2, 1e-12)   (D = 128, one wave per row)
// ---------------------------------------------------------------------------
__global__ __launch_bounds__(256) void norm_kernel(const float* __restrict__ h,
                                                   float* __restrict__ z)
{
    const int row = (blockIdx.x * 256 + threadIdx.x) >> 6;
    const int lane = threadIdx.x & 63;
    if (row >= NNODES) return;
    const float* hr = h + (size_t)row * 128;
    float v0 = hr[lane], v1 = hr[lane + 64];
    float ss = v0 * v0 + v1 * v1;
#pragma unroll
    for (int o = 32; o; o >>= 1) ss += __shfl_down(ss, o);
    ss = __shfl(ss, 0);
    float invn = 1.0f / fmaxf(sqrtf(ss), 1e-12f);
    z[(size_t)row * 128 + lane]      = v0 * invn;
    z[(size_t)row * 128 + lane + 64] = v1 * invn;
}

// ---------------------------------------------------------------------------
// A_pred = sigmoid(z @ z^T),  z: 8192x128.  64x64 tile per block, BK=32.
// ---------------------------------------------------------------------------
__global__ __launch_bounds__(256) void apred_kernel(const float* __restrict__ z,
                                                    float* __restrict__ out)
{
    __shared__ float sA[32][68];   // sA[k][row]
    __shared__ float sB[32][68];   // sB[k][col]

    const int tid = threadIdx.x;
    const int tx = tid & 15, ty = tid >> 4;
    const int bm = blockIdx.x * 64, bn = blockIdx.y * 64;

    float acc[4][4] = {};

    for (int k0 = 0; k0 < 128; k0 += 32) {
        for (int l = tid; l < 64 * 32; l += 256) {
            int r = l >> 5, kk = l & 31;
            sA[kk][r] = z[(size_t)(bm + r) * 128 + k0 + kk];
            sB[kk][r] = z[(size_t)(bn + r) * 128 + k0 + kk];
        }
        __syncthreads();
#pragma unroll
        for (int kk = 0; kk < 32; ++kk) {
            float a[4], b[4];
#pragma unroll
            for (int i = 0; i < 4; ++i) a[i] = sA[kk][ty * 4 + i];
#pragma unroll
            for (int j = 0; j < 4; ++j) b[j] = sB[kk][tx * 4 + j];
#pragma unroll
            for (int i = 0; i < 4; ++i)
#pragma unroll
                for (int j = 0; j < 4; ++j) acc[i][j] += a[i] * b[j];
        }
        __syncthreads();
    }

#pragma unroll
    for (int i = 0; i < 4; ++i) {
        float4 v;
        v.x = 1.0f / (1.0f + expf(-acc[i][0]));
        v.y = 1.0f / (1.0f + expf(-acc[i][1]));
        v.z = 1.0f / (1.0f + expf(-acc[i][2]));
        v.w = 1.0f / (1.0f + expf(-acc[i][3]));
        *(float4*)&out[(size_t)(bm + ty * 4 + i) * NNODES + bn + tx * 4] = v;
    }
}

// ---------------------------------------------------------------------------
extern "C" void kernel_launch(void* const* d_in, const int* in_sizes, int n_in,
                              void* d_out, int out_size, void* d_ws, size_t ws_size,
                              hipStream_t stream)
{
    const float* x   = (const float*)d_in[0];
    const float* adj = (const float*)d_in[1];
    const float* Mm  = (const float*)d_in[2];
    const float* W1  = (const float*)d_in[3];
    const float* as1 = (const float*)d_in[4];
    const float* an1 = (const float*)d_in[5];
    const float* W2  = (const float*)d_in[6];
    const float* as2 = (const float*)d_in[7];
    const float* an2 = (const float*)d_in[8];

    float* out   = (float*)d_out;
    float* Apred = out;                              // 8192*8192
    float* z     = out + (size_t)NNODES * NNODES;    // 8192*128

    float* ws  = (float*)d_ws;
    float* h1  = ws;                                 // 8192*512 (also reused as h2)
    float* h1p = h1 + (size_t)NNODES * 512;          // 8192*512
    float* h2p = h1p + (size_t)NNODES * 512;         // 8192*128
    float* sv  = h2p + (size_t)NNODES * 128;         // 8192
    float* nv  = sv + NNODES;                        // 8192

    // ---- layer 1 (D=512) ----
    gemm64<<<dim3(128, 8), 256, 0, stream>>>(x, W1, h1, NNODES, 512, 512);
    sn_kernel<512><<<dim3(2048), 256, 0, stream>>>(h1, as1, an1, sv, nv);
    attn_kernel<512><<<dim3(NNODES), 256, 0, stream>>>(adj, Mm, sv, nv, h1, h1p);

    // ---- layer 2 (D=128) ----
    gemm64<<<dim3(128, 2), 256, 0, stream>>>(h1p, W2, h1, NNODES, 128, 512);
    sn_kernel<128><<<dim3(2048), 256, 0, stream>>>(h1, as2, an2, sv, nv);
    attn_kernel<128><<<dim3(NNODES), 256, 0, stream>>>(adj, Mm, sv, nv, h1, h2p);

    // ---- decoder ----
    norm_kernel<<<dim3(2048), 256, 0, stream>>>(h2p, z);
    apred_kernel<<<dim3(128, 128), 256, 0, stream>>>(z, Apred);
}

// Round 2
// 1386.743 us; speedup vs baseline: 1.5039x; 1.5039x over previous
//
#include <hip/hip_runtime.h>
#include <math.h>

#define NNODES 8192
#define CAP 1024   // max neighbors/row stored in CSR (true max ~490 at 5% density)

// ---------------------------------------------------------------------------
// Generic tiled f32 GEMM: C[MxN] = A[MxK] @ B[KxN], all row-major.
// 64x64 C-tile per 256-thread block, BK=16, 4x4 micro-tile per thread.
// ---------------------------------------------------------------------------
__global__ __launch_bounds__(256) void gemm64(const float* __restrict__ A,
                                              const float* __restrict__ B,
                                              float* __restrict__ C,
                                              int M, int N, int K)
{
    __shared__ float sA[16][68];
    __shared__ float sB[16][68];

    const int tid = threadIdx.x;
    const int tx = tid & 15, ty = tid >> 4;
    const int bm = blockIdx.x * 64, bn = blockIdx.y * 64;

    float acc[4][4] = {};

    for (int k0 = 0; k0 < K; k0 += 16) {
        for (int l = tid; l < 64 * 16; l += 256) {
            int m = l >> 4, k = l & 15;
            sA[k][m] = A[(size_t)(bm + m) * K + k0 + k];
        }
        for (int l = tid; l < 16 * 64; l += 256) {
            int k = l >> 6, n = l & 63;
            sB[k][n] = B[(size_t)(k0 + k) * N + bn + n];
        }
        __syncthreads();
#pragma unroll
        for (int k = 0; k < 16; ++k) {
            float a[4], b[4];
#pragma unroll
            for (int i = 0; i < 4; ++i) a[i] = sA[k][ty * 4 + i];
#pragma unroll
            for (int j = 0; j < 4; ++j) b[j] = sB[k][tx * 4 + j];
#pragma unroll
            for (int i = 0; i < 4; ++i)
#pragma unroll
                for (int j = 0; j < 4; ++j) acc[i][j] += a[i] * b[j];
        }
        __syncthreads();
    }

#pragma unroll
    for (int i = 0; i < 4; ++i) {
        float4 v = make_float4(acc[i][0], acc[i][1], acc[i][2], acc[i][3]);
        *(float4*)&C[(size_t)(bm + ty * 4 + i) * N + bn + tx * 4] = v;
    }
}

// ---------------------------------------------------------------------------
// s = h @ a_self, n = h @ a_neigh  (one wave per row)
// ---------------------------------------------------------------------------
template <int D>
__global__ __launch_bounds__(256) void sn_kernel(const float* __restrict__ h,
                                                 const float* __restrict__ a_s,
                                                 const float* __restrict__ a_n,
                                                 float* __restrict__ sv,
                                                 float* __restrict__ nv)
{
    const int row = (blockIdx.x * 256 + threadIdx.x) >> 6;
    const int lane = threadIdx.x & 63;
    if (row >= NNODES) return;
    const float* hr = h + (size_t)row * D;
    float a0 = 0.f, a1 = 0.f;
#pragma unroll
    for (int k = lane; k < D; k += 64) {
        float hv = hr[k];
        a0 += hv * a_s[k];
        a1 += hv * a_n[k];
    }
#pragma unroll
    for (int o = 32; o; o >>= 1) {
        a0 += __shfl_down(a0, o);
        a1 += __shfl_down(a1, o);
    }
    if (lane == 0) { sv[row] = a0; nv[row] = a1; }
}

// ---------------------------------------------------------------------------
// One-time CSR build: cols[i][k] = j-th nonzero column of adj row i (u16),
// vals[i][k] = M[i][j] there. Deterministic interleaved order.
// ---------------------------------------------------------------------------
__global__ __launch_bounds__(256) void build_csr(const float* __restrict__ adj,
                                                 const float* __restrict__ Mm,
                                                 unsigned short* __restrict__ cols,
                                                 float* __restrict__ vals,
                                                 int* __restrict__ nnzs)
{
    constexpr int NT = 256;
    __shared__ int scan[NT];
    __shared__ int tot;
    const int tid = threadIdx.x;
    const int i = blockIdx.x;
    const size_t rowoff = (size_t)i * NNODES;

    int myc = 0;
    for (int j = tid; j < NNODES; j += NT)
        myc += (adj[rowoff + j] > 0.f) ? 1 : 0;

    // Hillis-Steele inclusive scan over 256 counts
    scan[tid] = myc;
    __syncthreads();
    for (int o = 1; o < NT; o <<= 1) {
        int v = (tid >= o) ? scan[tid - o] : 0;
        __syncthreads();
        scan[tid] += v;
        __syncthreads();
    }
    int off = scan[tid] - myc;           // exclusive prefix
    if (tid == NT - 1) tot = scan[tid];
    __syncthreads();
    if (tid == 0) nnzs[i] = tot;

    const size_t base = (size_t)i * CAP;
    for (int j = tid; j < NNODES; j += NT) {
        float a = adj[rowoff + j];
        if (a > 0.f) {
            if (off < CAP) {
                cols[base + off] = (unsigned short)j;
                vals[base + off] = Mm[rowoff + j];
            }
            ++off;
        }
    }
}

// ---------------------------------------------------------------------------
// CSR attention row: out[i,:] = elu( softmax_k(e_ik) @ h[cols_k,:] )
// e_k = leakyrelu((s_i + n_{col_k}) * Mval_k). One 256-thread block per row.
// ---------------------------------------------------------------------------
template <int D>
__global__ __launch_bounds__(256) void attn_csr(const unsigned short* __restrict__ cols,
                                                const float* __restrict__ vals,
                                                const int* __restrict__ nnzs,
                                                const float* __restrict__ sv,
                                                const float* __restrict__ nv,
                                                const float* __restrict__ h,
                                                float* __restrict__ out)
{
    constexpr int NT = 256;
    __shared__ unsigned short scol[CAP];
    __shared__ float sp[CAP];
    __shared__ float reds[4];
    __shared__ float fb;
    __shared__ float part[NT];

    const int tid = threadIdx.x;
    const int i = blockIdx.x;
    const int nnz = min(nnzs[i], CAP);
    const float si = sv[i];
    const size_t base = (size_t)i * CAP;

    // ---- scores into LDS + row max ----
    float lmax = -3.0e38f;
    for (int k = tid; k < nnz; k += NT) {
        unsigned short c = cols[base + k];
        float e = (si + nv[c]) * vals[base + k];
        e = e > 0.f ? e : 0.2f * e;
        scol[k] = c;
        sp[k] = e;
        lmax = fmaxf(lmax, e);
    }
#pragma unroll
    for (int o = 32; o; o >>= 1) lmax = fmaxf(lmax, __shfl_down(lmax, o));
    if ((tid & 63) == 0) reds[tid >> 6] = lmax;
    __syncthreads();
    if (tid == 0) fb = fmaxf(fmaxf(reds[0], reds[1]), fmaxf(reds[2], reds[3]));
    __syncthreads();
    const float m = fb;

    // ---- exp + row sum ----
    float lsum = 0.f;
    for (int k = tid; k < nnz; k += NT) {
        float p = expf(sp[k] - m);
        sp[k] = p;
        lsum += p;
    }
#pragma unroll
    for (int o = 32; o; o >>= 1) lsum += __shfl_down(lsum, o);
    if ((tid & 63) == 0) reds[tid >> 6] = lsum;
    __syncthreads();
    if (tid == 0) fb = reds[0] + reds[1] + reds[2] + reds[3];
    __syncthreads();
    const float inv = 1.0f / fb;

    // ---- sparse PV gather + scale + ELU ----
    if constexpr (D == 512) {
        const int c = tid;
        float acc0 = 0.f, acc1 = 0.f;
#pragma unroll 4
        for (int k = 0; k < nnz; ++k) {
            float pj = sp[k];
            const float* hr = h + (size_t)scol[k] * 512;
            acc0 += pj * hr[c];
            acc1 += pj * hr[c + 256];
        }
        float r0 = acc0 * inv, r1 = acc1 * inv;
        out[(size_t)i * 512 + c]       = r0 > 0.f ? r0 : expm1f(r0);
        out[(size_t)i * 512 + c + 256] = r1 > 0.f ? r1 : expm1f(r1);
    } else {  // D == 128: two 128-thread groups split the k range
        const int halfsel = tid >> 7;
        const int c = tid & 127;
        float acc = 0.f;
#pragma unroll 4
        for (int k = halfsel; k < nnz; k += 2)
            acc += sp[k] * h[(size_t)scol[k] * 128 + c];
        part[tid] = acc;
        __syncthreads();
        if (tid < 128) {
            float r = (part[tid] + part[tid + 128]) * inv;
            out[(size_t)i * 128 + tid] = r > 0.f ? r : expm1f(r);
        }
    }
}

// ---------------------------------------------------------------------------
// Fallback dense attention (round-1 path), used only if ws is too small.
// ---------------------------------------------------------------------------
template <int D>
__global__ __launch_bounds__(256) void attn_kernel(const float* __restrict__ adj,
                                                   const float* __restrict__ Mm,
                                                   const float* __restrict__ sv,
                                                   const float* __restrict__ nv,
                                                   const float* __restrict__ h,
                                                   float* __restrict__ out)
{
    constexpr int NT = 256;
    constexpr int DCAP = 2048;
    __shared__ float pbuf[NNODES];
    __shared__ int   idxb[DCAP];
    __shared__ int   cnts[NT];
    __shared__ float reds[4];
    __shared__ float fbcast;
    __shared__ int   totc;

    const int tid = threadIdx.x;
    const int i = blockIdx.x;
    const size_t rowoff = (size_t)i * NNODES;
    const float si = sv[i];

    float lmax = -3.0e38f;
    for (int j = tid; j < NNODES; j += NT) {
        float a = adj[rowoff + j];
        float val = -9.0e15f;
        if (a > 0.f) {
            float e = (si + nv[j]) * Mm[rowoff + j];
            val = e > 0.f ? e : 0.2f * e;
            lmax = fmaxf(lmax, val);
        }
        pbuf[j] = val;
    }
#pragma unroll
    for (int o = 32; o; o >>= 1) lmax = fmaxf(lmax, __shfl_down(lmax, o));
    if ((tid & 63) == 0) reds[tid >> 6] = lmax;
    __syncthreads();
    if (tid == 0) fbcast = fmaxf(fmaxf(reds[0], reds[1]), fmaxf(reds[2], reds[3]));
    __syncthreads();
    const float m = fbcast;

    float lsum = 0.f;
    int myc = 0;
    for (int j = tid; j < NNODES; j += NT) {
        float v = pbuf[j];
        float p = (v > -8.9e15f) ? expf(v - m) : 0.f;
        pbuf[j] = p;
        lsum += p;
        if (p > 0.f) myc++;
    }
#pragma unroll
    for (int o = 32; o; o >>= 1) lsum += __shfl_down(lsum, o);
    if ((tid & 63) == 0) reds[tid >> 6] = lsum;
    cnts[tid] = myc;
    __syncthreads();
    if (tid == 0) {
        fbcast = reds[0] + reds[1] + reds[2] + reds[3];
        int run = 0;
        for (int t = 0; t < NT; ++t) { int c = cnts[t]; cnts[t] = run; run += c; }
        totc = run;
    }
    __syncthreads();
    const float inv = 1.0f / fbcast;
    const int nnz = totc;

    if (nnz <= DCAP) {
        int off = cnts[tid];
        for (int j = tid; j < NNODES; j += NT)
            if (pbuf[j] > 0.f) idxb[off++] = j;
    }
    __syncthreads();

    if constexpr (D == 512) {
        const int c = tid;
        float acc0 = 0.f, acc1 = 0.f;
        if (nnz <= DCAP) {
#pragma unroll 4
            for (int t = 0; t < nnz; ++t) {
                int j = idxb[t];
                float pj = pbuf[j];
                const float* hr = h + (size_t)j * 512;
                acc0 += pj * hr[c];
                acc1 += pj * hr[c + 256];
            }
        } else {
            for (int j = 0; j < NNODES; ++j) {
                float pj = pbuf[j];
                if (pj > 0.f) {
                    const float* hr = h + (size_t)j * 512;
                    acc0 += pj * hr[c];
                    acc1 += pj * hr[c + 256];
                }
            }
        }
        float r0 = acc0 * inv, r1 = acc1 * inv;
        out[(size_t)i * 512 + c]       = r0 > 0.f ? r0 : expm1f(r0);
        out[(size_t)i * 512 + c + 256] = r1 > 0.f ? r1 : expm1f(r1);
    } else {
        const int half = tid >> 7;
        const int c = tid & 127;
        float acc = 0.f;
        if (nnz <= DCAP) {
#pragma unroll 4
            for (int t = half; t < nnz; t += 2) {
                int j = idxb[t];
                acc += pbuf[j] * h[(size_t)j * 128 + c];
            }
        } else {
            for (int j = half; j < NNODES; j += 2) {
                float pj = pbuf[j];
                if (pj > 0.f) acc += pj * h[(size_t)j * 128 + c];
            }
        }
        __syncthreads();
        pbuf[tid] = acc;
        __syncthreads();
        if (tid < 128) {
            float r = (pbuf[tid] + pbuf[tid + 128]) * inv;
            out[(size_t)i * 128 + tid] = r > 0.f ? r : expm1f(r);
        }
    }
}

// ---------------------------------------------------------------------------
// z = h / max(||h||_2, 1e-12)   (D = 128, one wave per row)
// ---------------------------------------------------------------------------
__global__ __launch_bounds__(256) void norm_kernel(const float* __restrict__ h,
                                                   float* __restrict__ z)
{
    const int row = (blockIdx.x * 256 + threadIdx.x) >> 6;
    const int lane = threadIdx.x & 63;
    if (row >= NNODES) return;
    const float* hr = h + (size_t)row * 128;
    float v0 = hr[lane], v1 = hr[lane + 64];
    float ss = v0 * v0 + v1 * v1;
#pragma unroll
    for (int o = 32; o; o >>= 1) ss += __shfl_down(ss, o);
    ss = __shfl(ss, 0);
    float invn = 1.0f / fmaxf(sqrtf(ss), 1e-12f);
    z[(size_t)row * 128 + lane]      = v0 * invn;
    z[(size_t)row * 128 + lane + 64] = v1 * invn;
}

// ---------------------------------------------------------------------------
// A_pred = sigmoid(z @ z^T),  z: 8192x128.  64x64 tile per block, BK=32.
// ---------------------------------------------------------------------------
__global__ __launch_bounds__(256) void apred_kernel(const float* __restrict__ z,
                                                    float* __restrict__ out)
{
    __shared__ float sA[32][68];
    __shared__ float sB[32][68];

    const int tid = threadIdx.x;
    const int tx = tid & 15, ty = tid >> 4;
    const int bm = blockIdx.x * 64, bn = blockIdx.y * 64;

    float acc[4][4] = {};

    for (int k0 = 0; k0 < 128; k0 += 32) {
        for (int l = tid; l < 64 * 32; l += 256) {
            int r = l >> 5, kk = l & 31;
            sA[kk][r] = z[(size_t)(bm + r) * 128 + k0 + kk];
            sB[kk][r] = z[(size_t)(bn + r) * 128 + k0 + kk];
        }
        __syncthreads();
#pragma unroll
        for (int kk = 0; kk < 32; ++kk) {
            float a[4], b[4];
#pragma unroll
            for (int i = 0; i < 4; ++i) a[i] = sA[kk][ty * 4 + i];
#pragma unroll
            for (int j = 0; j < 4; ++j) b[j] = sB[kk][tx * 4 + j];
#pragma unroll
            for (int i = 0; i < 4; ++i)
#pragma unroll
                for (int j = 0; j < 4; ++j) acc[i][j] += a[i] * b[j];
        }
        __syncthreads();
    }

#pragma unroll
    for (int i = 0; i < 4; ++i) {
        float4 v;
        v.x = 1.0f / (1.0f + expf(-acc[i][0]));
        v.y = 1.0f / (1.0f + expf(-acc[i][1]));
        v.z = 1.0f / (1.0f + expf(-acc[i][2]));
        v.w = 1.0f / (1.0f + expf(-acc[i][3]));
        *(float4*)&out[(size_t)(bm + ty * 4 + i) * NNODES + bn + tx * 4] = v;
    }
}

// ---------------------------------------------------------------------------
extern "C" void kernel_launch(void* const* d_in, const int* in_sizes, int n_in,
                              void* d_out, int out_size, void* d_ws, size_t ws_size,
                              hipStream_t stream)
{
    const float* x   = (const float*)d_in[0];
    const float* adj = (const float*)d_in[1];
    const float* Mm  = (const float*)d_in[2];
    const float* W1  = (const float*)d_in[3];
    const float* as1 = (const float*)d_in[4];
    const float* an1 = (const float*)d_in[5];
    const float* W2  = (const float*)d_in[6];
    const float* as2 = (const float*)d_in[7];
    const float* an2 = (const float*)d_in[8];

    float* out   = (float*)d_out;
    float* Apred = out;
    float* z     = out + (size_t)NNODES * NNODES;

    // ---- workspace layout ----
    // floats: h1 (8192*512) | h1p (8192*512) | h2p (8192*128) | sv | nv | vals (8192*CAP)
    // then:   cols (8192*CAP u16) | nnzs (8192 int)
    float* ws  = (float*)d_ws;
    float* h1  = ws;
    float* h1p = h1 + (size_t)NNODES * 512;
    float* h2p = h1p + (size_t)NNODES * 512;
    float* sv  = h2p + (size_t)NNODES * 128;
    float* nv  = sv + NNODES;
    float* vals = nv + NNODES;
    unsigned short* cols = (unsigned short*)(vals + (size_t)NNODES * CAP);
    int* nnzs = (int*)(cols + (size_t)NNODES * CAP);

    const size_t need = (size_t)((char*)(nnzs + NNODES) - (char*)d_ws);

    if (ws_size >= need) {
        // one-time sparsity structure
        build_csr<<<dim3(NNODES), 256, 0, stream>>>(adj, Mm, cols, vals, nnzs);

        // layer 1 (D=512)
        gemm64<<<dim3(128, 8), 256, 0, stream>>>(x, W1, h1, NNODES, 512, 512);
        sn_kernel<512><<<dim3(2048), 256, 0, stream>>>(h1, as1, an1, sv, nv);
        attn_csr<512><<<dim3(NNODES), 256, 0, stream>>>(cols, vals, nnzs, sv, nv, h1, h1p);

        // layer 2 (D=128)
        gemm64<<<dim3(128, 2), 256, 0, stream>>>(h1p, W2, h1, NNODES, 128, 512);
        sn_kernel<128><<<dim3(2048), 256, 0, stream>>>(h1, as2, an2, sv, nv);
        attn_csr<128><<<dim3(NNODES), 256, 0, stream>>>(cols, vals, nnzs, sv, nv, h1, h2p);
    } else {
        // fallback: dense per-row scan (round-1 path)
        gemm64<<<dim3(128, 8), 256, 0, stream>>>(x, W1, h1, NNODES, 512, 512);
        sn_kernel<512><<<dim3(2048), 256, 0, stream>>>(h1, as1, an1, sv, nv);
        attn_kernel<512><<<dim3(NNODES), 256, 0, stream>>>(adj, Mm, sv, nv, h1, h1p);

        gemm64<<<dim3(128, 2), 256, 0, stream>>>(h1p, W2, h1, NNODES, 128, 512);
        sn_kernel<128><<<dim3(2048), 256, 0, stream>>>(h1, as2, an2, sv, nv);
        attn_kernel<128><<<dim3(NNODES), 256, 0, stream>>>(adj, Mm, sv, nv, h1, h2p);
    }

    // decoder
    norm_kernel<<<dim3(2048), 256, 0, stream>>>(h2p, z);
    apred_kernel<<<dim3(128, 128), 256, 0, stream>>>(z, Apred);
}

// Round 3
// 762.484 us; speedup vs baseline: 2.7351x; 1.8187x over previous
//
#include <hip/hip_runtime.h>
#include <math.h>

#define NNODES 8192
#define CAP 1024   // max neighbors/row in CSR (true max ~490 at 5% density)

typedef __attribute__((ext_vector_type(8))) short bf16x8;
typedef __attribute__((ext_vector_type(4))) float f32x4;
typedef unsigned short ushort_t;

__device__ inline unsigned short f2bf(float x) {
    unsigned u = __builtin_bit_cast(unsigned, x);
    u += 0x7fffu + ((u >> 16) & 1u);   // RNE
    return (unsigned short)(u >> 16);
}

#define GLOAD_LDS16(g, l)                                                      \
    __builtin_amdgcn_global_load_lds(                                          \
        (const __attribute__((address_space(1))) void*)(g),                    \
        (__attribute__((address_space(3))) void*)(l), 16, 0, 0)

// Stage a [ROWS][64]-bf16 tile (128B rows, 8 chunks of 16B) into LDS with
// XOR swizzle: physical chunk = logical chunk ^ (row&7). LDS dest is linear
// in lane order (global_load_lds requirement); the swizzle is applied by
// pre-swizzling the per-lane GLOBAL source (guide §5 / m173 pattern).
template <int ROWS>
__device__ inline void stage_tile(ushort_t* lds, const ushort_t* g, size_t ld, int tid)
{
#pragma unroll
    for (int c = 0; c < ROWS / 32; ++c) {
        int row = c * 32 + (tid >> 3);
        int lch = (tid & 7) ^ (row & 7);
        GLOAD_LDS16(g + (size_t)row * ld + lch * 8, lds + (size_t)c * 2048 + tid * 8);
    }
}

// swizzled LDS read offset (in ushorts) for logical (row, kchunk)
__device__ inline int swz_off(int row, int kc) {
    return row * 64 + ((kc ^ (row & 7)) * 8);
}

// ---------------------------------------------------------------------------
// f32 tiled GEMM (x@W1, h1p@W2): C[MxN] = A[MxK] @ B[KxN]
// ---------------------------------------------------------------------------
__global__ __launch_bounds__(256) void gemm64(const float* __restrict__ A,
                                              const float* __restrict__ B,
                                              float* __restrict__ C,
                                              int M, int N, int K)
{
    __shared__ float sA[16][68];
    __shared__ float sB[16][68];

    const int tid = threadIdx.x;
    const int tx = tid & 15, ty = tid >> 4;
    const int bm = blockIdx.x * 64, bn = blockIdx.y * 64;

    float acc[4][4] = {};

    for (int k0 = 0; k0 < K; k0 += 16) {
        for (int l = tid; l < 64 * 16; l += 256) {
            int m = l >> 4, k = l & 15;
            sA[k][m] = A[(size_t)(bm + m) * K + k0 + k];
        }
        for (int l = tid; l < 16 * 64; l += 256) {
            int k = l >> 6, n = l & 63;
            sB[k][n] = B[(size_t)(k0 + k) * N + bn + n];
        }
        __syncthreads();
#pragma unroll
        for (int k = 0; k < 16; ++k) {
            float a[4], b[4];
#pragma unroll
            for (int i = 0; i < 4; ++i) a[i] = sA[k][ty * 4 + i];
#pragma unroll
            for (int j = 0; j < 4; ++j) b[j] = sB[k][tx * 4 + j];
#pragma unroll
            for (int i = 0; i < 4; ++i)
#pragma unroll
                for (int j = 0; j < 4; ++j) acc[i][j] += a[i] * b[j];
        }
        __syncthreads();
    }

#pragma unroll
    for (int i = 0; i < 4; ++i) {
        float4 v = make_float4(acc[i][0], acc[i][1], acc[i][2], acc[i][3]);
        *(float4*)&C[(size_t)(bm + ty * 4 + i) * N + bn + tx * 4] = v;
    }
}

// ---------------------------------------------------------------------------
// s = h @ a_self, n = h @ a_neigh  (one wave per row)
// ---------------------------------------------------------------------------
template <int D>
__global__ __launch_bounds__(256) void sn_kernel(const float* __restrict__ h,
                                                 const float* __restrict__ a_s,
                                                 const float* __restrict__ a_n,
                                                 float* __restrict__ sv,
                                                 float* __restrict__ nv)
{
    const int row = (blockIdx.x * 256 + threadIdx.x) >> 6;
    const int lane = threadIdx.x & 63;
    if (row >= NNODES) return;
    const float* hr = h + (size_t)row * D;
    float a0 = 0.f, a1 = 0.f;
#pragma unroll
    for (int k = lane; k < D; k += 64) {
        float hv = hr[k];
        a0 += hv * a_s[k];
        a1 += hv * a_n[k];
    }
#pragma unroll
    for (int o = 32; o; o >>= 1) {
        a0 += __shfl_down(a0, o);
        a1 += __shfl_down(a1, o);
    }
    if (lane == 0) { sv[row] = a0; nv[row] = a1; }
}

// ---------------------------------------------------------------------------
// One-time CSR build
// ---------------------------------------------------------------------------
__global__ __launch_bounds__(256) void build_csr(const float* __restrict__ adj,
                                                 const float* __restrict__ Mm,
                                                 unsigned short* __restrict__ cols,
                                                 float* __restrict__ vals,
                                                 int* __restrict__ nnzs)
{
    constexpr int NT = 256;
    __shared__ int scan[NT];
    __shared__ int tot;
    const int tid = threadIdx.x;
    const int i = blockIdx.x;
    const size_t rowoff = (size_t)i * NNODES;

    int myc = 0;
    for (int j = tid; j < NNODES; j += NT)
        myc += (adj[rowoff + j] > 0.f) ? 1 : 0;

    scan[tid] = myc;
    __syncthreads();
    for (int o = 1; o < NT; o <<= 1) {
        int v = (tid >= o) ? scan[tid - o] : 0;
        __syncthreads();
        scan[tid] += v;
        __syncthreads();
    }
    int off = scan[tid] - myc;
    if (tid == NT - 1) tot = scan[tid];
    __syncthreads();
    if (tid == 0) nnzs[i] = tot;

    const size_t base = (size_t)i * CAP;
    for (int j = tid; j < NNODES; j += NT) {
        float a = adj[rowoff + j];
        if (a > 0.f) {
            if (off < CAP) {
                cols[base + off] = (unsigned short)j;
                vals[base + off] = Mm[rowoff + j];
            }
            ++off;
        }
    }
}

// ---------------------------------------------------------------------------
// Row softmax on CSR, scatter normalized probs (bf16) into dense P (zeroed).
// ---------------------------------------------------------------------------
__global__ __launch_bounds__(256) void softmax_csr(const unsigned short* __restrict__ cols,
                                                   const float* __restrict__ vals,
                                                   const int* __restrict__ nnzs,
                                                   const float* __restrict__ sv,
                                                   const float* __restrict__ nv,
                                                   ushort_t* __restrict__ P)
{
    constexpr int NT = 256;
    __shared__ unsigned short scol[CAP];
    __shared__ float sp[CAP];
    __shared__ float reds[4];
    __shared__ float fb;

    const int tid = threadIdx.x;
    const int i = blockIdx.x;
    const int nnz = min(nnzs[i], CAP);
    const float si = sv[i];
    const size_t base = (size_t)i * CAP;

    float lmax = -3.0e38f;
    for (int k = tid; k < nnz; k += NT) {
        unsigned short c = cols[base + k];
        float e = (si + nv[c]) * vals[base + k];
        e = e > 0.f ? e : 0.2f * e;
        scol[k] = c;
        sp[k] = e;
        lmax = fmaxf(lmax, e);
    }
#pragma unroll
    for (int o = 32; o; o >>= 1) lmax = fmaxf(lmax, __shfl_down(lmax, o));
    if ((tid & 63) == 0) reds[tid >> 6] = lmax;
    __syncthreads();
    if (tid == 0) fb = fmaxf(fmaxf(reds[0], reds[1]), fmaxf(reds[2], reds[3]));
    __syncthreads();
    const float m = fb;

    float lsum = 0.f;
    for (int k = tid; k < nnz; k += NT) {
        float p = expf(sp[k] - m);
        sp[k] = p;
        lsum += p;
    }
#pragma unroll
    for (int o = 32; o; o >>= 1) lsum += __shfl_down(lsum, o);
    if ((tid & 63) == 0) reds[tid >> 6] = lsum;
    __syncthreads();
    if (tid == 0) fb = reds[0] + reds[1] + reds[2] + reds[3];
    __syncthreads();
    const float inv = 1.0f / fb;

    const size_t rowoff = (size_t)i * NNODES;
    for (int k = tid; k < nnz; k += NT)
        P[rowoff + scol[k]] = f2bf(sp[k] * inv);
}

// ---------------------------------------------------------------------------
// h1 [8192][512] f32  ->  hbT [512][8192] bf16 (transposed cast)
// ---------------------------------------------------------------------------
__global__ __launch_bounds__(256) void cast_T(const float* __restrict__ h,
                                              ushort_t* __restrict__ hbT)
{
    __shared__ ushort_t t[64][66];
    const int bi = blockIdx.x;   // k block (128)
    const int bj = blockIdx.y;   // n block (8)
    const int c = threadIdx.x & 63, r4 = threadIdx.x >> 6;
#pragma unroll
    for (int i = 0; i < 16; ++i) {
        int r = i * 4 + r4;
        t[r][c] = f2bf(h[(size_t)(bi * 64 + r) * 512 + bj * 64 + c]);
    }
    __syncthreads();
#pragma unroll
    for (int i = 0; i < 16; ++i) {
        int r = i * 4 + r4;
        hbT[(size_t)(bj * 64 + r) * 8192 + bi * 64 + c] = t[c][r];
    }
}

// ---------------------------------------------------------------------------
// h1p = elu(P @ h1)  via bf16 MFMA.  P: [8192][8192] bf16, hbT: [512][8192].
// BM=128, BN=64, BK=64. 4 waves (2x2), wave tile 64x32 (4x2 16x16 frags).
// ---------------------------------------------------------------------------
__global__ __launch_bounds__(256) void gemm_pv(const ushort_t* __restrict__ P,
                                               const ushort_t* __restrict__ hbT,
                                               float* __restrict__ out)
{
    __shared__ __align__(16) ushort_t At[128 * 64];
    __shared__ __align__(16) ushort_t Bt[64 * 64];

    const int tid = threadIdx.x;
    const int wid = tid >> 6, lane = tid & 63;
    const int wr = wid >> 1, wc = wid & 1;
    const int bm = blockIdx.x * 128;
    const int bn = blockIdx.y * 64;

    f32x4 acc[4][2] = {};

    for (int k0 = 0; k0 < NNODES; k0 += 64) {
        stage_tile<128>(At, P + (size_t)bm * NNODES + k0, NNODES, tid);
        stage_tile<64>(Bt, hbT + (size_t)bn * NNODES + k0, NNODES, tid);
        __syncthreads();
#pragma unroll
        for (int kk = 0; kk < 2; ++kk) {
            const int kc = kk * 4 + (lane >> 4);
            bf16x8 af[4], bfr[2];
#pragma unroll
            for (int m = 0; m < 4; ++m) {
                int r = wr * 64 + m * 16 + (lane & 15);
                af[m] = *(const bf16x8*)&At[swz_off(r, kc)];
            }
#pragma unroll
            for (int n = 0; n < 2; ++n) {
                int r = wc * 32 + n * 16 + (lane & 15);
                bfr[n] = *(const bf16x8*)&Bt[swz_off(r, kc)];
            }
#pragma unroll
            for (int m = 0; m < 4; ++m)
#pragma unroll
                for (int n = 0; n < 2; ++n)
                    acc[m][n] = __builtin_amdgcn_mfma_f32_16x16x32_bf16(af[m], bfr[n], acc[m][n], 0, 0, 0);
        }
        __syncthreads();
    }

#pragma unroll
    for (int m = 0; m < 4; ++m)
#pragma unroll
        for (int n = 0; n < 2; ++n)
#pragma unroll
            for (int r_ = 0; r_ < 4; ++r_) {
                int row = bm + wr * 64 + m * 16 + (lane >> 4) * 4 + r_;
                int col = bn + wc * 32 + n * 16 + (lane & 15);
                float v = acc[m][n][r_];
                out[(size_t)row * 512 + col] = v > 0.f ? v : expm1f(v);
            }
}

// ---------------------------------------------------------------------------
// A_pred = sigmoid(z @ z^T) via bf16 MFMA. zb: [8192][128] bf16.
// BM=BN=128, BK=64 (2 iters). 4 waves (2x2), wave tile 64x64 (4x4 frags).
// ---------------------------------------------------------------------------
__global__ __launch_bounds__(256) void apred_mfma(const ushort_t* __restrict__ zb,
                                                  float* __restrict__ out)
{
    __shared__ __align__(16) ushort_t At[128 * 64];
    __shared__ __align__(16) ushort_t Bt[128 * 64];

    const int tid = threadIdx.x;
    const int wid = tid >> 6, lane = tid & 63;
    const int wr = wid >> 1, wc = wid & 1;
    const int bm = blockIdx.x * 128;
    const int bn = blockIdx.y * 128;

    f32x4 acc[4][4] = {};

#pragma unroll
    for (int k0 = 0; k0 < 128; k0 += 64) {
        stage_tile<128>(At, zb + (size_t)bm * 128 + k0, 128, tid);
        stage_tile<128>(Bt, zb + (size_t)bn * 128 + k0, 128, tid);
        __syncthreads();
#pragma unroll
        for (int kk = 0; kk < 2; ++kk) {
            const int kc = kk * 4 + (lane >> 4);
            bf16x8 af[4], bfr[4];
#pragma unroll
            for (int m = 0; m < 4; ++m) {
                int r = wr * 64 + m * 16 + (lane & 15);
                af[m] = *(const bf16x8*)&At[swz_off(r, kc)];
            }
#pragma unroll
            for (int n = 0; n < 4; ++n) {
                int r = wc * 64 + n * 16 + (lane & 15);
                bfr[n] = *(const bf16x8*)&Bt[swz_off(r, kc)];
            }
#pragma unroll
            for (int m = 0; m < 4; ++m)
#pragma unroll
                for (int n = 0; n < 4; ++n)
                    acc[m][n] = __builtin_amdgcn_mfma_f32_16x16x32_bf16(af[m], bfr[n], acc[m][n], 0, 0, 0);
        }
        __syncthreads();
    }

#pragma unroll
    for (int m = 0; m < 4; ++m)
#pragma unroll
        for (int n = 0; n < 4; ++n)
#pragma unroll
            for (int r_ = 0; r_ < 4; ++r_) {
                int row = bm + wr * 64 + m * 16 + (lane >> 4) * 4 + r_;
                int col = bn + wc * 64 + n * 16 + (lane & 15);
                float v = acc[m][n][r_];
                out[(size_t)row * NNODES + col] = 1.0f / (1.0f + expf(-v));
            }
}

// ---------------------------------------------------------------------------
// CSR attention (f32 gather) — used for layer 2 (D=128)
// ---------------------------------------------------------------------------
template <int D>
__global__ __launch_bounds__(256) void attn_csr(const unsigned short* __restrict__ cols,
                                                const float* __restrict__ vals,
                                                const int* __restrict__ nnzs,
                                                const float* __restrict__ sv,
                                                const float* __restrict__ nv,
                                                const float* __restrict__ h,
                                                float* __restrict__ out)
{
    constexpr int NT = 256;
    __shared__ unsigned short scol[CAP];
    __shared__ float sp[CAP];
    __shared__ float reds[4];
    __shared__ float fb;
    __shared__ float part[NT];

    const int tid = threadIdx.x;
    const int i = blockIdx.x;
    const int nnz = min(nnzs[i], CAP);
    const float si = sv[i];
    const size_t base = (size_t)i * CAP;

    float lmax = -3.0e38f;
    for (int k = tid; k < nnz; k += NT) {
        unsigned short c = cols[base + k];
        float e = (si + nv[c]) * vals[base + k];
        e = e > 0.f ? e : 0.2f * e;
        scol[k] = c;
        sp[k] = e;
        lmax = fmaxf(lmax, e);
    }
#pragma unroll
    for (int o = 32; o; o >>= 1) lmax = fmaxf(lmax, __shfl_down(lmax, o));
    if ((tid & 63) == 0) reds[tid >> 6] = lmax;
    __syncthreads();
    if (tid == 0) fb = fmaxf(fmaxf(reds[0], reds[1]), fmaxf(reds[2], reds[3]));
    __syncthreads();
    const float m = fb;

    float lsum = 0.f;
    for (int k = tid; k < nnz; k += NT) {
        float p = expf(sp[k] - m);
        sp[k] = p;
        lsum += p;
    }
#pragma unroll
    for (int o = 32; o; o >>= 1) lsum += __shfl_down(lsum, o);
    if ((tid & 63) == 0) reds[tid >> 6] = lsum;
    __syncthreads();
    if (tid == 0) fb = reds[0] + reds[1] + reds[2] + reds[3];
    __syncthreads();
    const float inv = 1.0f / fb;

    if constexpr (D == 512) {
        const int c = tid;
        float acc0 = 0.f, acc1 = 0.f;
#pragma unroll 4
        for (int k = 0; k < nnz; ++k) {
            float pj = sp[k];
            const float* hr = h + (size_t)scol[k] * 512;
            acc0 += pj * hr[c];
            acc1 += pj * hr[c + 256];
        }
        float r0 = acc0 * inv, r1 = acc1 * inv;
        out[(size_t)i * 512 + c]       = r0 > 0.f ? r0 : expm1f(r0);
        out[(size_t)i * 512 + c + 256] = r1 > 0.f ? r1 : expm1f(r1);
    } else {
        const int halfsel = tid >> 7;
        const int c = tid & 127;
        float acc = 0.f;
#pragma unroll 4
        for (int k = halfsel; k < nnz; k += 2)
            acc += sp[k] * h[(size_t)scol[k] * 128 + c];
        part[tid] = acc;
        __syncthreads();
        if (tid < 128) {
            float r = (part[tid] + part[tid + 128]) * inv;
            out[(size_t)i * 128 + tid] = r > 0.f ? r : expm1f(r);
        }
    }
}

// ---------------------------------------------------------------------------
// z = h / max(||h||,1e-12); also writes bf16 copy zb
// ---------------------------------------------------------------------------
__global__ __launch_bounds__(256) void norm_kernel(const float* __restrict__ h,
                                                   float* __restrict__ z,
                                                   ushort_t* __restrict__ zb)
{
    const int row = (blockIdx.x * 256 + threadIdx.x) >> 6;
    const int lane = threadIdx.x & 63;
    if (row >= NNODES) return;
    const float* hr = h + (size_t)row * 128;
    float v0 = hr[lane], v1 = hr[lane + 64];
    float ss = v0 * v0 + v1 * v1;
#pragma unroll
    for (int o = 32; o; o >>= 1) ss += __shfl_down(ss, o);
    ss = __shfl(ss, 0);
    float invn = 1.0f / fmaxf(sqrtf(ss), 1e-12f);
    float z0 = v0 * invn, z1 = v1 * invn;
    z[(size_t)row * 128 + lane]      = z0;
    z[(size_t)row * 128 + lane + 64] = z1;
    zb[(size_t)row * 128 + lane]      = f2bf(z0);
    zb[(size_t)row * 128 + lane + 64] = f2bf(z1);
}

// ---------------------------------------------------------------------------
// Fallback dense attention (round-1 path) — only if ws is too small.
// ---------------------------------------------------------------------------
template <int D>
__global__ __launch_bounds__(256) void attn_kernel(const float* __restrict__ adj,
                                                   const float* __restrict__ Mm,
                                                   const float* __restrict__ sv,
                                                   const float* __restrict__ nv,
                                                   const float* __restrict__ h,
                                                   float* __restrict__ out)
{
    constexpr int NT = 256;
    constexpr int DCAP = 2048;
    __shared__ float pbuf[NNODES];
    __shared__ int   idxb[DCAP];
    __shared__ int   cnts[NT];
    __shared__ float reds[4];
    __shared__ float fbcast;
    __shared__ int   totc;

    const int tid = threadIdx.x;
    const int i = blockIdx.x;
    const size_t rowoff = (size_t)i * NNODES;
    const float si = sv[i];

    float lmax = -3.0e38f;
    for (int j = tid; j < NNODES; j += NT) {
        float a = adj[rowoff + j];
        float val = -9.0e15f;
        if (a > 0.f) {
            float e = (si + nv[j]) * Mm[rowoff + j];
            val = e > 0.f ? e : 0.2f * e;
            lmax = fmaxf(lmax, val);
        }
        pbuf[j] = val;
    }
#pragma unroll
    for (int o = 32; o; o >>= 1) lmax = fmaxf(lmax, __shfl_down(lmax, o));
    if ((tid & 63) == 0) reds[tid >> 6] = lmax;
    __syncthreads();
    if (tid == 0) fbcast = fmaxf(fmaxf(reds[0], reds[1]), fmaxf(reds[2], reds[3]));
    __syncthreads();
    const float m = fbcast;

    float lsum = 0.f;
    int myc = 0;
    for (int j = tid; j < NNODES; j += NT) {
        float v = pbuf[j];
        float p = (v > -8.9e15f) ? expf(v - m) : 0.f;
        pbuf[j] = p;
        lsum += p;
        if (p > 0.f) myc++;
    }
#pragma unroll
    for (int o = 32; o; o >>= 1) lsum += __shfl_down(lsum, o);
    if ((tid & 63) == 0) reds[tid >> 6] = lsum;
    cnts[tid] = myc;
    __syncthreads();
    if (tid == 0) {
        fbcast = reds[0] + reds[1] + reds[2] + reds[3];
        int run = 0;
        for (int t = 0; t < NT; ++t) { int c = cnts[t]; cnts[t] = run; run += c; }
        totc = run;
    }
    __syncthreads();
    const float inv = 1.0f / fbcast;
    const int nnz = totc;

    if (nnz <= DCAP) {
        int off = cnts[tid];
        for (int j = tid; j < NNODES; j += NT)
            if (pbuf[j] > 0.f) idxb[off++] = j;
    }
    __syncthreads();

    if constexpr (D == 512) {
        const int c = tid;
        float acc0 = 0.f, acc1 = 0.f;
        if (nnz <= DCAP) {
#pragma unroll 4
            for (int t = 0; t < nnz; ++t) {
                int j = idxb[t];
                float pj = pbuf[j];
                const float* hr = h + (size_t)j * 512;
                acc0 += pj * hr[c];
                acc1 += pj * hr[c + 256];
            }
        } else {
            for (int j = 0; j < NNODES; ++j) {
                float pj = pbuf[j];
                if (pj > 0.f) {
                    const float* hr = h + (size_t)j * 512;
                    acc0 += pj * hr[c];
                    acc1 += pj * hr[c + 256];
                }
            }
        }
        float r0 = acc0 * inv, r1 = acc1 * inv;
        out[(size_t)i * 512 + c]       = r0 > 0.f ? r0 : expm1f(r0);
        out[(size_t)i * 512 + c + 256] = r1 > 0.f ? r1 : expm1f(r1);
    } else {
        const int half = tid >> 7;
        const int c = tid & 127;
        float acc = 0.f;
        if (nnz <= DCAP) {
#pragma unroll 4
            for (int t = half; t < nnz; t += 2) {
                int j = idxb[t];
                acc += pbuf[j] * h[(size_t)j * 128 + c];
            }
        } else {
            for (int j = half; j < NNODES; j += 2) {
                float pj = pbuf[j];
                if (pj > 0.f) acc += pj * h[(size_t)j * 128 + c];
            }
        }
        __syncthreads();
        pbuf[tid] = acc;
        __syncthreads();
        if (tid < 128) {
            float r = (pbuf[tid] + pbuf[tid + 128]) * inv;
            out[(size_t)i * 128 + tid] = r > 0.f ? r : expm1f(r);
        }
    }
}

// ---------------------------------------------------------------------------
// f32 apred fallback
// ---------------------------------------------------------------------------
__global__ __launch_bounds__(256) void apred_kernel(const float* __restrict__ z,
                                                    float* __restrict__ out)
{
    __shared__ float sA[32][68];
    __shared__ float sB[32][68];

    const int tid = threadIdx.x;
    const int tx = tid & 15, ty = tid >> 4;
    const int bm = blockIdx.x * 64, bn = blockIdx.y * 64;

    float acc[4][4] = {};

    for (int k0 = 0; k0 < 128; k0 += 32) {
        for (int l = tid; l < 64 * 32; l += 256) {
            int r = l >> 5, kk = l & 31;
            sA[kk][r] = z[(size_t)(bm + r) * 128 + k0 + kk];
            sB[kk][r] = z[(size_t)(bn + r) * 128 + k0 + kk];
        }
        __syncthreads();
#pragma unroll
        for (int kk = 0; kk < 32; ++kk) {
            float a[4], b[4];
#pragma unroll
            for (int i = 0; i < 4; ++i) a[i] = sA[kk][ty * 4 + i];
#pragma unroll
            for (int j = 0; j < 4; ++j) b[j] = sB[kk][tx * 4 + j];
#pragma unroll
            for (int i = 0; i < 4; ++i)
#pragma unroll
                for (int j = 0; j < 4; ++j) acc[i][j] += a[i] * b[j];
        }
        __syncthreads();
    }

#pragma unroll
    for (int i = 0; i < 4; ++i) {
        float4 v;
        v.x = 1.0f / (1.0f + expf(-acc[i][0]));
        v.y = 1.0f / (1.0f + expf(-acc[i][1]));
        v.z = 1.0f / (1.0f + expf(-acc[i][2]));
        v.w = 1.0f / (1.0f + expf(-acc[i][3]));
        *(float4*)&out[(size_t)(bm + ty * 4 + i) * NNODES + bn + tx * 4] = v;
    }
}

// ---------------------------------------------------------------------------
extern "C" void kernel_launch(void* const* d_in, const int* in_sizes, int n_in,
                              void* d_out, int out_size, void* d_ws, size_t ws_size,
                              hipStream_t stream)
{
    const float* x   = (const float*)d_in[0];
    const float* adj = (const float*)d_in[1];
    const float* Mm  = (const float*)d_in[2];
    const float* W1  = (const float*)d_in[3];
    const float* as1 = (const float*)d_in[4];
    const float* an1 = (const float*)d_in[5];
    const float* W2  = (const float*)d_in[6];
    const float* as2 = (const float*)d_in[7];
    const float* an2 = (const float*)d_in[8];

    float* out   = (float*)d_out;
    float* Apred = out;
    float* z     = out + (size_t)NNODES * NNODES;

    // Scratch inside the Apred output region (dead until decoder):
    //   P   bf16 8192x8192  = 128 MiB   at offset 0
    //   hbT bf16 512x8192   = 8 MiB     at offset 128 MiB
    ushort_t* P   = (ushort_t*)Apred;
    ushort_t* hbT = (ushort_t*)((char*)Apred + (size_t)134217728);

    // ws layout
    float* ws  = (float*)d_ws;
    float* h1  = ws;                                  // 8192*512 f32 (reused as h2)
    float* h1p = h1 + (size_t)NNODES * 512;           // 8192*512 f32
    float* h2p = h1p + (size_t)NNODES * 512;          // 8192*128 f32
    float* sv  = h2p + (size_t)NNODES * 128;
    float* nv  = sv + NNODES;
    float* vals = nv + NNODES;                        // 8192*CAP f32
    unsigned short* cols = (unsigned short*)(vals + (size_t)NNODES * CAP);
    int* nnzs = (int*)(cols + (size_t)NNODES * CAP);
    ushort_t* zb = (ushort_t*)(nnzs + NNODES);        // 8192*128 bf16

    const size_t need = (size_t)((char*)(zb + (size_t)NNODES * 128) - (char*)d_ws);

    if (ws_size >= need) {
        build_csr<<<dim3(NNODES), 256, 0, stream>>>(adj, Mm, cols, vals, nnzs);

        // layer 1
        gemm64<<<dim3(128, 8), 256, 0, stream>>>(x, W1, h1, NNODES, 512, 512);
        sn_kernel<512><<<dim3(2048), 256, 0, stream>>>(h1, as1, an1, sv, nv);
        hipMemsetAsync(P, 0, (size_t)NNODES * NNODES * 2, stream);
        softmax_csr<<<dim3(NNODES), 256, 0, stream>>>(cols, vals, nnzs, sv, nv, P);
        cast_T<<<dim3(128, 8), 256, 0, stream>>>(h1, hbT);
        gemm_pv<<<dim3(64, 8), 256, 0, stream>>>(P, hbT, h1p);

        // layer 2
        gemm64<<<dim3(128, 2), 256, 0, stream>>>(h1p, W2, h1, NNODES, 128, 512);
        sn_kernel<128><<<dim3(2048), 256, 0, stream>>>(h1, as2, an2, sv, nv);
        attn_csr<128><<<dim3(NNODES), 256, 0, stream>>>(cols, vals, nnzs, sv, nv, h1, h2p);

        // decoder
        norm_kernel<<<dim3(2048), 256, 0, stream>>>(h2p, z, zb);
        apred_mfma<<<dim3(64, 64), 256, 0, stream>>>(zb, Apred);
    } else {
        // minimal fallback: round-1 dense path (f32 everywhere)
        gemm64<<<dim3(128, 8), 256, 0, stream>>>(x, W1, h1, NNODES, 512, 512);
        sn_kernel<512><<<dim3(2048), 256, 0, stream>>>(h1, as1, an1, sv, nv);
        attn_kernel<512><<<dim3(NNODES), 256, 0, stream>>>(adj, Mm, sv, nv, h1, h1p);

        gemm64<<<dim3(128, 2), 256, 0, stream>>>(h1p, W2, h1, NNODES, 128, 512);
        sn_kernel<128><<<dim3(2048), 256, 0, stream>>>(h1, as2, an2, sv, nv);
        attn_kernel<128><<<dim3(NNODES), 256, 0, stream>>>(adj, Mm, sv, nv, h1, h2p);

        norm_kernel<<<dim3(2048), 256, 0, stream>>>(h2p, z, zb);
        apred_kernel<<<dim3(128, 128), 256, 0, stream>>>(z, Apred);
    }
}

// Round 4
// 742.998 us; speedup vs baseline: 2.8068x; 1.0262x over previous
//
#include <hip/hip_runtime.h>
#include <math.h>

#define NNODES 8192
#define CAP 1024   // max neighbors/row in CSR (true max ~500 at 5% density)

typedef __attribute__((ext_vector_type(8))) short bf16x8;
typedef __attribute__((ext_vector_type(4))) float f32x4;
typedef unsigned short ushort_t;

__device__ inline unsigned short f2bf(float x) {
    unsigned u = __builtin_bit_cast(unsigned, x);
    u += 0x7fffu + ((u >> 16) & 1u);   // RNE
    return (unsigned short)(u >> 16);
}
__device__ inline float bf2f(unsigned short b) {
    unsigned u = ((unsigned)b) << 16;
    return __builtin_bit_cast(float, u);
}

#define GLOAD_LDS16(g, l)                                                      \
    __builtin_amdgcn_global_load_lds(                                          \
        (const __attribute__((address_space(1))) void*)(g),                    \
        (__attribute__((address_space(3))) void*)(l), 16, 0, 0)

// Stage a [ROWS][64]-bf16 tile (128B rows, 8 chunks of 16B) into LDS with
// XOR swizzle: physical chunk = logical chunk ^ (row&7). LDS dest linear in
// lane order (global_load_lds requirement); swizzle applied on the global src.
template <int ROWS>
__device__ inline void stage_tile(ushort_t* lds, const ushort_t* g, size_t ld, int tid)
{
#pragma unroll
    for (int c = 0; c < ROWS / 32; ++c) {
        int row = c * 32 + (tid >> 3);
        int lch = (tid & 7) ^ (row & 7);
        GLOAD_LDS16(g + (size_t)row * ld + lch * 8, lds + (size_t)c * 2048 + tid * 8);
    }
}

__device__ inline int swz_off(int row, int kc) {
    return row * 64 + ((kc ^ (row & 7)) * 8);
}

// ---------------------------------------------------------------------------
// f32 tiled GEMM (x@W1, h1p@W2): C[MxN] = A[MxK] @ B[KxN]
// ---------------------------------------------------------------------------
__global__ __launch_bounds__(256) void gemm64(const float* __restrict__ A,
                                              const float* __restrict__ B,
                                              float* __restrict__ C,
                                              int M, int N, int K)
{
    __shared__ float sA[16][68];
    __shared__ float sB[16][68];

    const int tid = threadIdx.x;
    const int tx = tid & 15, ty = tid >> 4;
    const int bm = blockIdx.x * 64, bn = blockIdx.y * 64;

    float acc[4][4] = {};

    for (int k0 = 0; k0 < K; k0 += 16) {
        for (int l = tid; l < 64 * 16; l += 256) {
            int m = l >> 4, k = l & 15;
            sA[k][m] = A[(size_t)(bm + m) * K + k0 + k];
        }
        for (int l = tid; l < 16 * 64; l += 256) {
            int k = l >> 6, n = l & 63;
            sB[k][n] = B[(size_t)(k0 + k) * N + bn + n];
        }
        __syncthreads();
#pragma unroll
        for (int k = 0; k < 16; ++k) {
            float a[4], b[4];
#pragma unroll
            for (int i = 0; i < 4; ++i) a[i] = sA[k][ty * 4 + i];
#pragma unroll
            for (int j = 0; j < 4; ++j) b[j] = sB[k][tx * 4 + j];
#pragma unroll
            for (int i = 0; i < 4; ++i)
#pragma unroll
                for (int j = 0; j < 4; ++j) acc[i][j] += a[i] * b[j];
        }
        __syncthreads();
    }

#pragma unroll
    for (int i = 0; i < 4; ++i) {
        float4 v = make_float4(acc[i][0], acc[i][1], acc[i][2], acc[i][3]);
        *(float4*)&C[(size_t)(bm + ty * 4 + i) * N + bn + tx * 4] = v;
    }
}

// ---------------------------------------------------------------------------
// s = h @ a_self, n = h @ a_neigh  (one wave per row)
// ---------------------------------------------------------------------------
template <int D>
__global__ __launch_bounds__(256) void sn_kernel(const float* __restrict__ h,
                                                 const float* __restrict__ a_s,
                                                 const float* __restrict__ a_n,
                                                 float* __restrict__ sv,
                                                 float* __restrict__ nv)
{
    const int row = (blockIdx.x * 256 + threadIdx.x) >> 6;
    const int lane = threadIdx.x & 63;
    if (row >= NNODES) return;
    const float* hr = h + (size_t)row * D;
    float a0 = 0.f, a1 = 0.f;
#pragma unroll
    for (int k = lane; k < D; k += 64) {
        float hv = hr[k];
        a0 += hv * a_s[k];
        a1 += hv * a_n[k];
    }
#pragma unroll
    for (int o = 32; o; o >>= 1) {
        a0 += __shfl_down(a0, o);
        a1 += __shfl_down(a1, o);
    }
    if (lane == 0) { sv[row] = a0; nv[row] = a1; }
}

// ---------------------------------------------------------------------------
// CSR build, wave-per-row ballot compaction. Single pass, coalesced adj AND
// M reads (float4), deterministic ordering, no LDS, no barriers.
// ---------------------------------------------------------------------------
__global__ __launch_bounds__(256) void build_csr(const float* __restrict__ adj,
                                                 const float* __restrict__ Mm,
                                                 unsigned short* __restrict__ cols,
                                                 float* __restrict__ vals,
                                                 int* __restrict__ nnzs)
{
    const int lane = threadIdx.x & 63;
    const int row = blockIdx.x * 4 + (threadIdx.x >> 6);
    const float4* arow = (const float4*)(adj + (size_t)row * NNODES);
    const float4* mrow = (const float4*)(Mm + (size_t)row * NNODES);
    const size_t base = (size_t)row * CAP;
    const unsigned long long below = (1ull << lane) - 1ull;

    int off = 0;
    for (int c4 = 0; c4 < NNODES / 4; c4 += 64) {
        float4 a = arow[c4 + lane];
        float4 mv = mrow[c4 + lane];
#pragma unroll
        for (int e = 0; e < 4; ++e) {
            float ae = (&a.x)[e];
            unsigned long long mask = __ballot(ae > 0.f);
            if (ae > 0.f) {
                int pos = off + __popcll(mask & below);
                if (pos < CAP) {
                    cols[base + pos] = (unsigned short)((c4 + lane) * 4 + e);
                    vals[base + pos] = (&mv.x)[e];
                }
            }
            off += __popcll(mask);
        }
    }
    if (lane == 0) nnzs[row] = off;
}

// ---------------------------------------------------------------------------
// Row softmax on CSR, scatter normalized probs (bf16) into dense P (zeroed).
// ---------------------------------------------------------------------------
__global__ __launch_bounds__(256) void softmax_csr(const unsigned short* __restrict__ cols,
                                                   const float* __restrict__ vals,
                                                   const int* __restrict__ nnzs,
                                                   const float* __restrict__ sv,
                                                   const float* __restrict__ nv,
                                                   ushort_t* __restrict__ P)
{
    constexpr int NT = 256;
    __shared__ unsigned short scol[CAP];
    __shared__ float sp[CAP];
    __shared__ float reds[4];
    __shared__ float fb;

    const int tid = threadIdx.x;
    const int i = blockIdx.x;
    const int nnz = min(nnzs[i], CAP);
    const float si = sv[i];
    const size_t base = (size_t)i * CAP;

    float lmax = -3.0e38f;
    for (int k = tid; k < nnz; k += NT) {
        unsigned short c = cols[base + k];
        float e = (si + nv[c]) * vals[base + k];
        e = e > 0.f ? e : 0.2f * e;
        scol[k] = c;
        sp[k] = e;
        lmax = fmaxf(lmax, e);
    }
#pragma unroll
    for (int o = 32; o; o >>= 1) lmax = fmaxf(lmax, __shfl_down(lmax, o));
    if ((tid & 63) == 0) reds[tid >> 6] = lmax;
    __syncthreads();
    if (tid == 0) fb = fmaxf(fmaxf(reds[0], reds[1]), fmaxf(reds[2], reds[3]));
    __syncthreads();
    const float m = fb;

    float lsum = 0.f;
    for (int k = tid; k < nnz; k += NT) {
        float p = expf(sp[k] - m);
        sp[k] = p;
        lsum += p;
    }
#pragma unroll
    for (int o = 32; o; o >>= 1) lsum += __shfl_down(lsum, o);
    if ((tid & 63) == 0) reds[tid >> 6] = lsum;
    __syncthreads();
    if (tid == 0) fb = reds[0] + reds[1] + reds[2] + reds[3];
    __syncthreads();
    const float inv = 1.0f / fb;

    const size_t rowoff = (size_t)i * NNODES;
    for (int k = tid; k < nnz; k += NT)
        P[rowoff + scol[k]] = f2bf(sp[k] * inv);
}

// ---------------------------------------------------------------------------
// h1 [8192][512] f32  ->  hbT [512][8192] bf16 (transposed cast)
// ---------------------------------------------------------------------------
__global__ __launch_bounds__(256) void cast_T(const float* __restrict__ h,
                                              ushort_t* __restrict__ hbT)
{
    __shared__ ushort_t t[64][66];
    const int bi = blockIdx.x;   // k block (128)
    const int bj = blockIdx.y;   // n block (8)
    const int c = threadIdx.x & 63, r4 = threadIdx.x >> 6;
#pragma unroll
    for (int i = 0; i < 16; ++i) {
        int r = i * 4 + r4;
        t[r][c] = f2bf(h[(size_t)(bi * 64 + r) * 512 + bj * 64 + c]);
    }
    __syncthreads();
#pragma unroll
    for (int i = 0; i < 16; ++i) {
        int r = i * 4 + r4;
        hbT[(size_t)(bj * 64 + r) * 8192 + bi * 64 + c] = t[c][r];
    }
}

// ---------------------------------------------------------------------------
// flat f32 -> bf16 cast (4 elems/thread)
// ---------------------------------------------------------------------------
__global__ __launch_bounds__(256) void cast_bf(const float* __restrict__ in,
                                               ushort_t* __restrict__ out, int n4)
{
    int i = blockIdx.x * 256 + threadIdx.x;
    if (i >= n4) return;
    float4 v = ((const float4*)in)[i];
    ushort_t o[4] = { f2bf(v.x), f2bf(v.y), f2bf(v.z), f2bf(v.w) };
    *(uint2*)&out[(size_t)i * 4] = *(uint2*)o;
}

// ---------------------------------------------------------------------------
// h1p = elu(P @ h1) via bf16 MFMA. P: [8192][8192] bf16, hbT: [512][8192].
// BM=128, BN=128, BK=64. 4 waves (2x2), wave tile 64x64 (4x4 16x16 frags).
// Grid (bm=64, bn=4): bn-blocks sharing a P panel are = mod 8 -> same XCD.
// ---------------------------------------------------------------------------
__global__ __launch_bounds__(256) void gemm_pv(const ushort_t* __restrict__ P,
                                               const ushort_t* __restrict__ hbT,
                                               float* __restrict__ out)
{
    __shared__ __align__(16) ushort_t At[128 * 64];
    __shared__ __align__(16) ushort_t Bt[128 * 64];

    const int tid = threadIdx.x;
    const int wid = tid >> 6, lane = tid & 63;
    const int wr = wid >> 1, wc = wid & 1;
    const int bm = blockIdx.x * 128;
    const int bn = blockIdx.y * 128;

    f32x4 acc[4][4] = {};

    for (int k0 = 0; k0 < NNODES; k0 += 64) {
        stage_tile<128>(At, P + (size_t)bm * NNODES + k0, NNODES, tid);
        stage_tile<128>(Bt, hbT + (size_t)bn * NNODES + k0, NNODES, tid);
        __syncthreads();
#pragma unroll
        for (int kk = 0; kk < 2; ++kk) {
            const int kc = kk * 4 + (lane >> 4);
            bf16x8 af[4], bfr[4];
#pragma unroll
            for (int m = 0; m < 4; ++m) {
                int r = wr * 64 + m * 16 + (lane & 15);
                af[m] = *(const bf16x8*)&At[swz_off(r, kc)];
            }
#pragma unroll
            for (int n = 0; n < 4; ++n) {
                int r = wc * 64 + n * 16 + (lane & 15);
                bfr[n] = *(const bf16x8*)&Bt[swz_off(r, kc)];
            }
#pragma unroll
            for (int m = 0; m < 4; ++m)
#pragma unroll
                for (int n = 0; n < 4; ++n)
                    acc[m][n] = __builtin_amdgcn_mfma_f32_16x16x32_bf16(af[m], bfr[n], acc[m][n], 0, 0, 0);
        }
        __syncthreads();
    }

#pragma unroll
    for (int m = 0; m < 4; ++m)
#pragma unroll
        for (int n = 0; n < 4; ++n)
#pragma unroll
            for (int r_ = 0; r_ < 4; ++r_) {
                int row = bm + wr * 64 + m * 16 + (lane >> 4) * 4 + r_;
                int col = bn + wc * 64 + n * 16 + (lane & 15);
                float v = acc[m][n][r_];
                out[(size_t)row * 512 + col] = v > 0.f ? v : expm1f(v);
            }
}

// ---------------------------------------------------------------------------
// A_pred = sigmoid(z @ z^T) via bf16 MFMA. zb: [8192][128] bf16.
// ---------------------------------------------------------------------------
__global__ __launch_bounds__(256) void apred_mfma(const ushort_t* __restrict__ zb,
                                                  float* __restrict__ out)
{
    __shared__ __align__(16) ushort_t At[128 * 64];
    __shared__ __align__(16) ushort_t Bt[128 * 64];

    const int tid = threadIdx.x;
    const int wid = tid >> 6, lane = tid & 63;
    const int wr = wid >> 1, wc = wid & 1;
    const int bm = blockIdx.x * 128;
    const int bn = blockIdx.y * 128;

    f32x4 acc[4][4] = {};

#pragma unroll
    for (int k0 = 0; k0 < 128; k0 += 64) {
        stage_tile<128>(At, zb + (size_t)bm * 128 + k0, 128, tid);
        stage_tile<128>(Bt, zb + (size_t)bn * 128 + k0, 128, tid);
        __syncthreads();
#pragma unroll
        for (int kk = 0; kk < 2; ++kk) {
            const int kc = kk * 4 + (lane >> 4);
            bf16x8 af[4], bfr[4];
#pragma unroll
            for (int m = 0; m < 4; ++m) {
                int r = wr * 64 + m * 16 + (lane & 15);
                af[m] = *(const bf16x8*)&At[swz_off(r, kc)];
            }
#pragma unroll
            for (int n = 0; n < 4; ++n) {
                int r = wc * 64 + n * 16 + (lane & 15);
                bfr[n] = *(const bf16x8*)&Bt[swz_off(r, kc)];
            }
#pragma unroll
            for (int m = 0; m < 4; ++m)
#pragma unroll
                for (int n = 0; n < 4; ++n)
                    acc[m][n] = __builtin_amdgcn_mfma_f32_16x16x32_bf16(af[m], bfr[n], acc[m][n], 0, 0, 0);
        }
        __syncthreads();
    }

#pragma unroll
    for (int m = 0; m < 4; ++m)
#pragma unroll
        for (int n = 0; n < 4; ++n)
#pragma unroll
            for (int r_ = 0; r_ < 4; ++r_) {
                int row = bm + wr * 64 + m * 16 + (lane >> 4) * 4 + r_;
                int col = bn + wc * 64 + n * 16 + (lane & 15);
                float v = acc[m][n][r_];
                out[(size_t)row * NNODES + col] = 1.0f / (1.0f + expf(-v));
            }
}

// ---------------------------------------------------------------------------
// Layer-2 CSR attention: probs f32, PV gather from bf16 h table (2 MiB,
// L2-resident). 4 k-groups x 64 lanes; each lane covers 2 columns (uint).
// ---------------------------------------------------------------------------
__global__ __launch_bounds__(256) void attn2_csr(const unsigned short* __restrict__ cols,
                                                 const float* __restrict__ vals,
                                                 const int* __restrict__ nnzs,
                                                 const float* __restrict__ sv,
                                                 const float* __restrict__ nv,
                                                 const ushort_t* __restrict__ h2b,
                                                 float* __restrict__ out)
{
    constexpr int NT = 256;
    __shared__ unsigned short scol[CAP];
    __shared__ float sp[CAP];
    __shared__ float reds[4];
    __shared__ float fb;
    __shared__ float2 part[NT];

    const int tid = threadIdx.x;
    const int i = blockIdx.x;
    const int nnz = min(nnzs[i], CAP);
    const float si = sv[i];
    const size_t base = (size_t)i * CAP;

    float lmax = -3.0e38f;
    for (int k = tid; k < nnz; k += NT) {
        unsigned short c = cols[base + k];
        float e = (si + nv[c]) * vals[base + k];
        e = e > 0.f ? e : 0.2f * e;
        scol[k] = c;
        sp[k] = e;
        lmax = fmaxf(lmax, e);
    }
#pragma unroll
    for (int o = 32; o; o >>= 1) lmax = fmaxf(lmax, __shfl_down(lmax, o));
    if ((tid & 63) == 0) reds[tid >> 6] = lmax;
    __syncthreads();
    if (tid == 0) fb = fmaxf(fmaxf(reds[0], reds[1]), fmaxf(reds[2], reds[3]));
    __syncthreads();
    const float m = fb;

    float lsum = 0.f;
    for (int k = tid; k < nnz; k += NT) {
        float p = expf(sp[k] - m);
        sp[k] = p;
        lsum += p;
    }
#pragma unroll
    for (int o = 32; o; o >>= 1) lsum += __shfl_down(lsum, o);
    if ((tid & 63) == 0) reds[tid >> 6] = lsum;
    __syncthreads();
    if (tid == 0) fb = reds[0] + reds[1] + reds[2] + reds[3];
    __syncthreads();
    const float inv = 1.0f / fb;

    // PV: group g handles k = g, g+4, ...; lane covers cols {2*lane, 2*lane+1}
    const int g = tid >> 6, lane = tid & 63;
    float ax = 0.f, ay = 0.f;
    for (int k = g; k < nnz; k += 4) {
        float pj = sp[k];
        unsigned hv = *(const unsigned*)&h2b[(size_t)scol[k] * 128 + lane * 2];
        ax += pj * __builtin_bit_cast(float, hv << 16);
        ay += pj * __builtin_bit_cast(float, hv & 0xffff0000u);
    }
    part[tid] = make_float2(ax, ay);
    __syncthreads();
    if (tid < 64) {
        float2 r0 = part[tid], r1 = part[tid + 64], r2 = part[tid + 128], r3 = part[tid + 192];
        float vx = (r0.x + r1.x + r2.x + r3.x) * inv;
        float vy = (r0.y + r1.y + r2.y + r3.y) * inv;
        out[(size_t)i * 128 + tid * 2]     = vx > 0.f ? vx : expm1f(vx);
        out[(size_t)i * 128 + tid * 2 + 1] = vy > 0.f ? vy : expm1f(vy);
    }
}

// ---------------------------------------------------------------------------
// z = h / max(||h||,1e-12); also writes bf16 copy zb
// ---------------------------------------------------------------------------
__global__ __launch_bounds__(256) void norm_kernel(const float* __restrict__ h,
                                                   float* __restrict__ z,
                                                   ushort_t* __restrict__ zb)
{
    const int row = (blockIdx.x * 256 + threadIdx.x) >> 6;
    const int lane = threadIdx.x & 63;
    if (row >= NNODES) return;
    const float* hr = h + (size_t)row * 128;
    float v0 = hr[lane], v1 = hr[lane + 64];
    float ss = v0 * v0 + v1 * v1;
#pragma unroll
    for (int o = 32; o; o >>= 1) ss += __shfl_down(ss, o);
    ss = __shfl(ss, 0);
    float invn = 1.0f / fmaxf(sqrtf(ss), 1e-12f);
    float z0 = v0 * invn, z1 = v1 * invn;
    z[(size_t)row * 128 + lane]      = z0;
    z[(size_t)row * 128 + lane + 64] = z1;
    zb[(size_t)row * 128 + lane]      = f2bf(z0);
    zb[(size_t)row * 128 + lane + 64] = f2bf(z1);
}

// ---------------------------------------------------------------------------
// Fallback dense attention (round-1 path) — only if ws is too small.
// ---------------------------------------------------------------------------
template <int D>
__global__ __launch_bounds__(256) void attn_kernel(const float* __restrict__ adj,
                                                   const float* __restrict__ Mm,
                                                   const float* __restrict__ sv,
                                                   const float* __restrict__ nv,
                                                   const float* __restrict__ h,
                                                   float* __restrict__ out)
{
    constexpr int NT = 256;
    constexpr int DCAP = 2048;
    __shared__ float pbuf[NNODES];
    __shared__ int   idxb[DCAP];
    __shared__ int   cnts[NT];
    __shared__ float reds[4];
    __shared__ float fbcast;
    __shared__ int   totc;

    const int tid = threadIdx.x;
    const int i = blockIdx.x;
    const size_t rowoff = (size_t)i * NNODES;
    const float si = sv[i];

    float lmax = -3.0e38f;
    for (int j = tid; j < NNODES; j += NT) {
        float a = adj[rowoff + j];
        float val = -9.0e15f;
        if (a > 0.f) {
            float e = (si + nv[j]) * Mm[rowoff + j];
            val = e > 0.f ? e : 0.2f * e;
            lmax = fmaxf(lmax, val);
        }
        pbuf[j] = val;
    }
#pragma unroll
    for (int o = 32; o; o >>= 1) lmax = fmaxf(lmax, __shfl_down(lmax, o));
    if ((tid & 63) == 0) reds[tid >> 6] = lmax;
    __syncthreads();
    if (tid == 0) fbcast = fmaxf(fmaxf(reds[0], reds[1]), fmaxf(reds[2], reds[3]));
    __syncthreads();
    const float m = fbcast;

    float lsum = 0.f;
    int myc = 0;
    for (int j = tid; j < NNODES; j += NT) {
        float v = pbuf[j];
        float p = (v > -8.9e15f) ? expf(v - m) : 0.f;
        pbuf[j] = p;
        lsum += p;
        if (p > 0.f) myc++;
    }
#pragma unroll
    for (int o = 32; o; o >>= 1) lsum += __shfl_down(lsum, o);
    if ((tid & 63) == 0) reds[tid >> 6] = lsum;
    cnts[tid] = myc;
    __syncthreads();
    if (tid == 0) {
        fbcast = reds[0] + reds[1] + reds[2] + reds[3];
        int run = 0;
        for (int t = 0; t < NT; ++t) { int c = cnts[t]; cnts[t] = run; run += c; }
        totc = run;
    }
    __syncthreads();
    const float inv = 1.0f / fbcast;
    const int nnz = totc;

    if (nnz <= DCAP) {
        int off = cnts[tid];
        for (int j = tid; j < NNODES; j += NT)
            if (pbuf[j] > 0.f) idxb[off++] = j;
    }
    __syncthreads();

    if constexpr (D == 512) {
        const int c = tid;
        float acc0 = 0.f, acc1 = 0.f;
        if (nnz <= DCAP) {
#pragma unroll 4
            for (int t = 0; t < nnz; ++t) {
                int j = idxb[t];
                float pj = pbuf[j];
                const float* hr = h + (size_t)j * 512;
                acc0 += pj * hr[c];
                acc1 += pj * hr[c + 256];
            }
        } else {
            for (int j = 0; j < NNODES; ++j) {
                float pj = pbuf[j];
                if (pj > 0.f) {
                    const float* hr = h + (size_t)j * 512;
                    acc0 += pj * hr[c];
                    acc1 += pj * hr[c + 256];
                }
            }
        }
        float r0 = acc0 * inv, r1 = acc1 * inv;
        out[(size_t)i * 512 + c]       = r0 > 0.f ? r0 : expm1f(r0);
        out[(size_t)i * 512 + c + 256] = r1 > 0.f ? r1 : expm1f(r1);
    } else {
        const int half = tid >> 7;
        const int c = tid & 127;
        float acc = 0.f;
        if (nnz <= DCAP) {
#pragma unroll 4
            for (int t = half; t < nnz; t += 2) {
                int j = idxb[t];
                acc += pbuf[j] * h[(size_t)j * 128 + c];
            }
        } else {
            for (int j = half; j < NNODES; j += 2) {
                float pj = pbuf[j];
                if (pj > 0.f) acc += pj * h[(size_t)j * 128 + c];
            }
        }
        __syncthreads();
        pbuf[tid] = acc;
        __syncthreads();
        if (tid < 128) {
            float r = (pbuf[tid] + pbuf[tid + 128]) * inv;
            out[(size_t)i * 128 + tid] = r > 0.f ? r : expm1f(r);
        }
    }
}

// ---------------------------------------------------------------------------
// f32 apred fallback
// ---------------------------------------------------------------------------
__global__ __launch_bounds__(256) void apred_kernel(const float* __restrict__ z,
                                                    float* __restrict__ out)
{
    __shared__ float sA[32][68];
    __shared__ float sB[32][68];

    const int tid = threadIdx.x;
    const int tx = tid & 15, ty = tid >> 4;
    const int bm = blockIdx.x * 64, bn = blockIdx.y * 64;

    float acc[4][4] = {};

    for (int k0 = 0; k0 < 128; k0 += 32) {
        for (int l = tid; l < 64 * 32; l += 256) {
            int r = l >> 5, kk = l & 31;
            sA[kk][r] = z[(size_t)(bm + r) * 128 + k0 + kk];
            sB[kk][r] = z[(size_t)(bn + r) * 128 + k0 + kk];
        }
        __syncthreads();
#pragma unroll
        for (int kk = 0; kk < 32; ++kk) {
            float a[4], b[4];
#pragma unroll
            for (int i = 0; i < 4; ++i) a[i] = sA[kk][ty * 4 + i];
#pragma unroll
            for (int j = 0; j < 4; ++j) b[j] = sB[kk][tx * 4 + j];
#pragma unroll
            for (int i = 0; i < 4; ++i)
#pragma unroll
                for (int j = 0; j < 4; ++j) acc[i][j] += a[i] * b[j];
        }
        __syncthreads();
    }

#pragma unroll
    for (int i = 0; i < 4; ++i) {
        float4 v;
        v.x = 1.0f / (1.0f + expf(-acc[i][0]));
        v.y = 1.0f / (1.0f + expf(-acc[i][1]));
        v.z = 1.0f / (1.0f + expf(-acc[i][2]));
        v.w = 1.0f / (1.0f + expf(-acc[i][3]));
        *(float4*)&out[(size_t)(bm + ty * 4 + i) * NNODES + bn + tx * 4] = v;
    }
}

// ---------------------------------------------------------------------------
extern "C" void kernel_launch(void* const* d_in, const int* in_sizes, int n_in,
                              void* d_out, int out_size, void* d_ws, size_t ws_size,
                              hipStream_t stream)
{
    const float* x   = (const float*)d_in[0];
    const float* adj = (const float*)d_in[1];
    const float* Mm  = (const float*)d_in[2];
    const float* W1  = (const float*)d_in[3];
    const float* as1 = (const float*)d_in[4];
    const float* an1 = (const float*)d_in[5];
    const float* W2  = (const float*)d_in[6];
    const float* as2 = (const float*)d_in[7];
    const float* an2 = (const float*)d_in[8];

    float* out   = (float*)d_out;
    float* Apred = out;
    float* z     = out + (size_t)NNODES * NNODES;

    // Scratch inside the Apred output region (dead until decoder):
    ushort_t* P   = (ushort_t*)Apred;                                  // 128 MiB
    ushort_t* hbT = (ushort_t*)((char*)Apred + (size_t)134217728);     // 8 MiB

    // ws layout
    float* ws  = (float*)d_ws;
    float* h1  = ws;                                  // 8192*512 f32 (reused as h2)
    float* h1p = h1 + (size_t)NNODES * 512;           // 8192*512 f32
    float* h2p = h1p + (size_t)NNODES * 512;          // 8192*128 f32
    float* sv  = h2p + (size_t)NNODES * 128;
    float* nv  = sv + NNODES;
    float* vals = nv + NNODES;                        // 8192*CAP f32
    unsigned short* cols = (unsigned short*)(vals + (size_t)NNODES * CAP);
    int* nnzs = (int*)(cols + (size_t)NNODES * CAP);
    ushort_t* zb = (ushort_t*)(nnzs + NNODES);        // 8192*128 bf16
    ushort_t* h2b = zb + (size_t)NNODES * 128;        // 8192*128 bf16

    const size_t need = (size_t)((char*)(h2b + (size_t)NNODES * 128) - (char*)d_ws);

    if (ws_size >= need) {
        build_csr<<<dim3(2048), 256, 0, stream>>>(adj, Mm, cols, vals, nnzs);

        // layer 1
        gemm64<<<dim3(128, 8), 256, 0, stream>>>(x, W1, h1, NNODES, 512, 512);
        sn_kernel<512><<<dim3(2048), 256, 0, stream>>>(h1, as1, an1, sv, nv);
        hipMemsetAsync(P, 0, (size_t)NNODES * NNODES * 2, stream);
        softmax_csr<<<dim3(NNODES), 256, 0, stream>>>(cols, vals, nnzs, sv, nv, P);
        cast_T<<<dim3(128, 8), 256, 0, stream>>>(h1, hbT);
        gemm_pv<<<dim3(64, 4), 256, 0, stream>>>(P, hbT, h1p);

        // layer 2
        gemm64<<<dim3(128, 2), 256, 0, stream>>>(h1p, W2, h1, NNODES, 128, 512);
        sn_kernel<128><<<dim3(2048), 256, 0, stream>>>(h1, as2, an2, sv, nv);
        cast_bf<<<dim3(1024), 256, 0, stream>>>(h1, h2b, NNODES * 128 / 4);
        attn2_csr<<<dim3(NNODES), 256, 0, stream>>>(cols, vals, nnzs, sv, nv, h2b, h2p);

        // decoder
        norm_kernel<<<dim3(2048), 256, 0, stream>>>(h2p, z, zb);
        apred_mfma<<<dim3(64, 64), 256, 0, stream>>>(zb, Apred);
    } else {
        // fallback: round-1 dense f32 path
        gemm64<<<dim3(128, 8), 256, 0, stream>>>(x, W1, h1, NNODES, 512, 512);
        sn_kernel<512><<<dim3(2048), 256, 0, stream>>>(h1, as1, an1, sv, nv);
        attn_kernel<512><<<dim3(NNODES), 256, 0, stream>>>(adj, Mm, sv, nv, h1, h1p);

        gemm64<<<dim3(128, 2), 256, 0, stream>>>(h1p, W2, h1, NNODES, 128, 512);
        sn_kernel<128><<<dim3(2048), 256, 0, stream>>>(h1, as2, an2, sv, nv);
        attn_kernel<128><<<dim3(NNODES), 256, 0, stream>>>(adj, Mm, sv, nv, h1, h2p);

        norm_kernel<<<dim3(2048), 256, 0, stream>>>(h2p, z, zb);
        apred_kernel<<<dim3(128, 128), 256, 0, stream>>>(z, Apred);
    }
}

// Round 5
// 627.040 us; speedup vs baseline: 3.3259x; 1.1849x over previous
//
#include <hip/hip_runtime.h>
#include <math.h>

#define NNODES 8192
#define CAP 1024   // max neighbors/row in CSR (true max ~500 at 5% density)

typedef __attribute__((ext_vector_type(8))) short bf16x8;
typedef __attribute__((ext_vector_type(4))) float f32x4;
typedef unsigned short ushort_t;

__device__ inline unsigned short f2bf(float x) {
    unsigned u = __builtin_bit_cast(unsigned, x);
    u += 0x7fffu + ((u >> 16) & 1u);   // RNE
    return (unsigned short)(u >> 16);
}

#define GLOAD_LDS16(g, l)                                                      \
    __builtin_amdgcn_global_load_lds(                                          \
        (const __attribute__((address_space(1))) void*)(g),                    \
        (__attribute__((address_space(3))) void*)(l), 16, 0, 0)

// Stage a [ROWS][64]-bf16 tile (128B rows, 8 chunks of 16B) into LDS with
// XOR swizzle: physical chunk = logical chunk ^ (row&7). LDS dest linear in
// lane order (global_load_lds requirement); swizzle applied on the global src.
template <int ROWS>
__device__ inline void stage_tile(ushort_t* lds, const ushort_t* g, size_t ld, int tid)
{
#pragma unroll
    for (int c = 0; c < ROWS / 32; ++c) {
        int row = c * 32 + (tid >> 3);
        int lch = (tid & 7) ^ (row & 7);
        GLOAD_LDS16(g + (size_t)row * ld + lch * 8, lds + (size_t)c * 2048 + tid * 8);
    }
}

__device__ inline int swz_off(int row, int kc) {
    return row * 64 + ((kc ^ (row & 7)) * 8);
}

// ---------------------------------------------------------------------------
// f32 tiled GEMM (layer-2 h1p@W2 only): C[MxN] = A[MxK] @ B[KxN]
// ---------------------------------------------------------------------------
__global__ __launch_bounds__(256) void gemm64(const float* __restrict__ A,
                                              const float* __restrict__ B,
                                              float* __restrict__ C,
                                              int M, int N, int K)
{
    __shared__ float sA[16][68];
    __shared__ float sB[16][68];

    const int tid = threadIdx.x;
    const int tx = tid & 15, ty = tid >> 4;
    const int bm = blockIdx.x * 64, bn = blockIdx.y * 64;

    float acc[4][4] = {};

    for (int k0 = 0; k0 < K; k0 += 16) {
        for (int l = tid; l < 64 * 16; l += 256) {
            int m = l >> 4, k = l & 15;
            sA[k][m] = A[(size_t)(bm + m) * K + k0 + k];
        }
        for (int l = tid; l < 16 * 64; l += 256) {
            int k = l >> 6, n = l & 63;
            sB[k][n] = B[(size_t)(k0 + k) * N + bn + n];
        }
        __syncthreads();
#pragma unroll
        for (int k = 0; k < 16; ++k) {
            float a[4], b[4];
#pragma unroll
            for (int i = 0; i < 4; ++i) a[i] = sA[k][ty * 4 + i];
#pragma unroll
            for (int j = 0; j < 4; ++j) b[j] = sB[k][tx * 4 + j];
#pragma unroll
            for (int i = 0; i < 4; ++i)
#pragma unroll
                for (int j = 0; j < 4; ++j) acc[i][j] += a[i] * b[j];
        }
        __syncthreads();
    }

#pragma unroll
    for (int i = 0; i < 4; ++i) {
        float4 v = make_float4(acc[i][0], acc[i][1], acc[i][2], acc[i][3]);
        *(float4*)&C[(size_t)(bm + ty * 4 + i) * N + bn + tx * 4] = v;
    }
}

// ---------------------------------------------------------------------------
// s = h @ a_self, n = h @ a_neigh  (one wave per row)
// ---------------------------------------------------------------------------
template <int D>
__global__ __launch_bounds__(256) void sn_kernel(const float* __restrict__ h,
                                                 const float* __restrict__ a_s,
                                                 const float* __restrict__ a_n,
                                                 float* __restrict__ sv,
                                                 float* __restrict__ nv)
{
    const int row = (blockIdx.x * 256 + threadIdx.x) >> 6;
    const int lane = threadIdx.x & 63;
    if (row >= NNODES) return;
    const float* hr = h + (size_t)row * D;
    float a0 = 0.f, a1 = 0.f;
#pragma unroll
    for (int k = lane; k < D; k += 64) {
        float hv = hr[k];
        a0 += hv * a_s[k];
        a1 += hv * a_n[k];
    }
#pragma unroll
    for (int o = 32; o; o >>= 1) {
        a0 += __shfl_down(a0, o);
        a1 += __shfl_down(a1, o);
    }
    if (lane == 0) { sv[row] = a0; nv[row] = a1; }
}

// ---------------------------------------------------------------------------
// CSR build, wave-per-row ballot compaction. 4x unrolled: 8 independent
// float4 loads in flight per wave for MLP. Coalesced adj AND M reads.
// ---------------------------------------------------------------------------
__global__ __launch_bounds__(256) void build_csr(const float* __restrict__ adj,
                                                 const float* __restrict__ Mm,
                                                 unsigned short* __restrict__ cols,
                                                 float* __restrict__ vals,
                                                 int* __restrict__ nnzs)
{
    const int lane = threadIdx.x & 63;
    const int row = blockIdx.x * 4 + (threadIdx.x >> 6);
    const float4* arow = (const float4*)(adj + (size_t)row * NNODES);
    const float4* mrow = (const float4*)(Mm + (size_t)row * NNODES);
    const size_t base = (size_t)row * CAP;
    const unsigned long long below = (1ull << lane) - 1ull;

    int off = 0;
    for (int c4 = 0; c4 < NNODES / 4; c4 += 256) {
        float4 a[4], mv[4];
#pragma unroll
        for (int u = 0; u < 4; ++u) {
            a[u]  = arow[c4 + u * 64 + lane];
            mv[u] = mrow[c4 + u * 64 + lane];
        }
#pragma unroll
        for (int u = 0; u < 4; ++u) {
#pragma unroll
            for (int e = 0; e < 4; ++e) {
                float ae = (&a[u].x)[e];
                unsigned long long mask = __ballot(ae > 0.f);
                if (ae > 0.f) {
                    int pos = off + __popcll(mask & below);
                    if (pos < CAP) {
                        cols[base + pos] = (unsigned short)((c4 + u * 64 + lane) * 4 + e);
                        vals[base + pos] = (&mv[u].x)[e];
                    }
                }
                off += __popcll(mask);
            }
        }
    }
    if (lane == 0) nnzs[row] = off;
}

// ---------------------------------------------------------------------------
// Row softmax on CSR; builds the dense bf16 P row in LDS and streams it out
// coalesced (fuses the old memset + scatter).
// ---------------------------------------------------------------------------
__global__ __launch_bounds__(256) void softmax_dense(const unsigned short* __restrict__ cols,
                                                     const float* __restrict__ vals,
                                                     const int* __restrict__ nnzs,
                                                     const float* __restrict__ sv,
                                                     const float* __restrict__ nv,
                                                     ushort_t* __restrict__ P)
{
    constexpr int NT = 256;
    __shared__ ushort_t drow[NNODES];      // 16 KB dense bf16 row
    __shared__ unsigned short scol[CAP];
    __shared__ float sp[CAP];
    __shared__ float reds[4];
    __shared__ float fb;

    const int tid = threadIdx.x;
    const int i = blockIdx.x;
    const int nnz = min(nnzs[i], CAP);
    const float si = sv[i];
    const size_t base = (size_t)i * CAP;

    // zero dense row (ordering vs scatter guaranteed by reduction syncs)
#pragma unroll
    for (int k = 0; k < NNODES / 8 / NT; ++k)
        ((uint4*)drow)[k * NT + tid] = (uint4){0u, 0u, 0u, 0u};

    float lmax = -3.0e38f;
    for (int k = tid; k < nnz; k += NT) {
        unsigned short c = cols[base + k];
        float e = (si + nv[c]) * vals[base + k];
        e = e > 0.f ? e : 0.2f * e;
        scol[k] = c;
        sp[k] = e;
        lmax = fmaxf(lmax, e);
    }
#pragma unroll
    for (int o = 32; o; o >>= 1) lmax = fmaxf(lmax, __shfl_down(lmax, o));
    if ((tid & 63) == 0) reds[tid >> 6] = lmax;
    __syncthreads();
    if (tid == 0) fb = fmaxf(fmaxf(reds[0], reds[1]), fmaxf(reds[2], reds[3]));
    __syncthreads();
    const float m = fb;

    float lsum = 0.f;
    for (int k = tid; k < nnz; k += NT) {
        float p = expf(sp[k] - m);
        sp[k] = p;
        lsum += p;
    }
#pragma unroll
    for (int o = 32; o; o >>= 1) lsum += __shfl_down(lsum, o);
    if ((tid & 63) == 0) reds[tid >> 6] = lsum;
    __syncthreads();
    if (tid == 0) fb = reds[0] + reds[1] + reds[2] + reds[3];
    __syncthreads();
    const float inv = 1.0f / fb;

    // scatter probs into LDS dense row
    for (int k = tid; k < nnz; k += NT)
        drow[scol[k]] = f2bf(sp[k] * inv);
    __syncthreads();

    // coalesced stream-out: 16 KB row
    uint4* dst = (uint4*)(P + (size_t)i * NNODES);
#pragma unroll
    for (int k = 0; k < NNODES / 8 / NT; ++k)
        dst[k * NT + tid] = ((const uint4*)drow)[k * NT + tid];
}

// ---------------------------------------------------------------------------
// Generic transpose-cast: in [R][C] f32 -> out [C][R] bf16. Grid (R/64, C/64).
// ---------------------------------------------------------------------------
__global__ __launch_bounds__(256) void tcast(const float* __restrict__ in,
                                             ushort_t* __restrict__ out,
                                             int R, int C)
{
    __shared__ ushort_t t[64][66];
    const int bi = blockIdx.x;   // row block of in
    const int bj = blockIdx.y;   // col block of in
    const int c = threadIdx.x & 63, r4 = threadIdx.x >> 6;
#pragma unroll
    for (int i = 0; i < 16; ++i) {
        int r = i * 4 + r4;
        t[r][c] = f2bf(in[(size_t)(bi * 64 + r) * C + bj * 64 + c]);
    }
    __syncthreads();
#pragma unroll
    for (int i = 0; i < 16; ++i) {
        int r = i * 4 + r4;
        out[(size_t)(bj * 64 + r) * R + bi * 64 + c] = t[c][r];
    }
}

// ---------------------------------------------------------------------------
// flat f32 -> bf16 cast (4 elems/thread)
// ---------------------------------------------------------------------------
__global__ __launch_bounds__(256) void cast_bf(const float* __restrict__ in,
                                               ushort_t* __restrict__ out, int n4)
{
    int i = blockIdx.x * 256 + threadIdx.x;
    if (i >= n4) return;
    float4 v = ((const float4*)in)[i];
    ushort_t o[4] = { f2bf(v.x), f2bf(v.y), f2bf(v.z), f2bf(v.w) };
    *(uint2*)&out[(size_t)i * 4] = *(uint2*)o;
}

// ---------------------------------------------------------------------------
// Generic bf16 MFMA GEMM: C[M x N] = A[M x K](bf16) @ BT[N x K](bf16)^T, f32 out.
// BM=BN=128, BK=64. 4 waves (2x2), wave tile 64x64 (4x4 16x16x32 frags).
// ELU=1 applies elu to outputs (PV path).
// ---------------------------------------------------------------------------
template <int ELU>
__global__ __launch_bounds__(256) void gemm_mfma(const ushort_t* __restrict__ A,
                                                 const ushort_t* __restrict__ BT,
                                                 float* __restrict__ C,
                                                 int N, int K)
{
    __shared__ __align__(16) ushort_t At[128 * 64];
    __shared__ __align__(16) ushort_t Bt[128 * 64];

    const int tid = threadIdx.x;
    const int wid = tid >> 6, lane = tid & 63;
    const int wr = wid >> 1, wc = wid & 1;
    const int bm = blockIdx.x * 128;
    const int bn = blockIdx.y * 128;

    f32x4 acc[4][4] = {};

    for (int k0 = 0; k0 < K; k0 += 64) {
        stage_tile<128>(At, A + (size_t)bm * K + k0, K, tid);
        stage_tile<128>(Bt, BT + (size_t)bn * K + k0, K, tid);
        __syncthreads();
#pragma unroll
        for (int kk = 0; kk < 2; ++kk) {
            const int kc = kk * 4 + (lane >> 4);
            bf16x8 af[4], bfr[4];
#pragma unroll
            for (int m = 0; m < 4; ++m) {
                int r = wr * 64 + m * 16 + (lane & 15);
                af[m] = *(const bf16x8*)&At[swz_off(r, kc)];
            }
#pragma unroll
            for (int n = 0; n < 4; ++n) {
                int r = wc * 64 + n * 16 + (lane & 15);
                bfr[n] = *(const bf16x8*)&Bt[swz_off(r, kc)];
            }
#pragma unroll
            for (int m = 0; m < 4; ++m)
#pragma unroll
                for (int n = 0; n < 4; ++n)
                    acc[m][n] = __builtin_amdgcn_mfma_f32_16x16x32_bf16(af[m], bfr[n], acc[m][n], 0, 0, 0);
        }
        __syncthreads();
    }

#pragma unroll
    for (int m = 0; m < 4; ++m)
#pragma unroll
        for (int n = 0; n < 4; ++n)
#pragma unroll
            for (int r_ = 0; r_ < 4; ++r_) {
                int row = bm + wr * 64 + m * 16 + (lane >> 4) * 4 + r_;
                int col = bn + wc * 64 + n * 16 + (lane & 15);
                float v = acc[m][n][r_];
                if (ELU) v = v > 0.f ? v : expm1f(v);
                C[(size_t)row * N + col] = v;
            }
}

// ---------------------------------------------------------------------------
// A_pred = sigmoid(z @ z^T) via bf16 MFMA. zb: [8192][128] bf16.
// ---------------------------------------------------------------------------
__global__ __launch_bounds__(256) void apred_mfma(const ushort_t* __restrict__ zb,
                                                  float* __restrict__ out)
{
    __shared__ __align__(16) ushort_t At[128 * 64];
    __shared__ __align__(16) ushort_t Bt[128 * 64];

    const int tid = threadIdx.x;
    const int wid = tid >> 6, lane = tid & 63;
    const int wr = wid >> 1, wc = wid & 1;
    const int bm = blockIdx.x * 128;
    const int bn = blockIdx.y * 128;

    f32x4 acc[4][4] = {};

#pragma unroll
    for (int k0 = 0; k0 < 128; k0 += 64) {
        stage_tile<128>(At, zb + (size_t)bm * 128 + k0, 128, tid);
        stage_tile<128>(Bt, zb + (size_t)bn * 128 + k0, 128, tid);
        __syncthreads();
#pragma unroll
        for (int kk = 0; kk < 2; ++kk) {
            const int kc = kk * 4 + (lane >> 4);
            bf16x8 af[4], bfr[4];
#pragma unroll
            for (int m = 0; m < 4; ++m) {
                int r = wr * 64 + m * 16 + (lane & 15);
                af[m] = *(const bf16x8*)&At[swz_off(r, kc)];
            }
#pragma unroll
            for (int n = 0; n < 4; ++n) {
                int r = wc * 64 + n * 16 + (lane & 15);
                bfr[n] = *(const bf16x8*)&Bt[swz_off(r, kc)];
            }
#pragma unroll
            for (int m = 0; m < 4; ++m)
#pragma unroll
                for (int n = 0; n < 4; ++n)
                    acc[m][n] = __builtin_amdgcn_mfma_f32_16x16x32_bf16(af[m], bfr[n], acc[m][n], 0, 0, 0);
        }
        __syncthreads();
    }

#pragma unroll
    for (int m = 0; m < 4; ++m)
#pragma unroll
        for (int n = 0; n < 4; ++n)
#pragma unroll
            for (int r_ = 0; r_ < 4; ++r_) {
                int row = bm + wr * 64 + m * 16 + (lane >> 4) * 4 + r_;
                int col = bn + wc * 64 + n * 16 + (lane & 15);
                float v = acc[m][n][r_];
                out[(size_t)row * NNODES + col] = 1.0f / (1.0f + expf(-v));
            }
}

// ---------------------------------------------------------------------------
// Layer-2 CSR attention: probs f32, PV gather from bf16 h table (2 MiB,
// L2-resident). 4 k-groups x 64 lanes; each lane covers 2 columns (uint).
// ---------------------------------------------------------------------------
__global__ __launch_bounds__(256) void attn2_csr(const unsigned short* __restrict__ cols,
                                                 const float* __restrict__ vals,
                                                 const int* __restrict__ nnzs,
                                                 const float* __restrict__ sv,
                                                 const float* __restrict__ nv,
                                                 const ushort_t* __restrict__ h2b,
                                                 float* __restrict__ out)
{
    constexpr int NT = 256;
    __shared__ unsigned short scol[CAP];
    __shared__ float sp[CAP];
    __shared__ float reds[4];
    __shared__ float fb;
    __shared__ float2 part[NT];

    const int tid = threadIdx.x;
    const int i = blockIdx.x;
    const int nnz = min(nnzs[i], CAP);
    const float si = sv[i];
    const size_t base = (size_t)i * CAP;

    float lmax = -3.0e38f;
    for (int k = tid; k < nnz; k += NT) {
        unsigned short c = cols[base + k];
        float e = (si + nv[c]) * vals[base + k];
        e = e > 0.f ? e : 0.2f * e;
        scol[k] = c;
        sp[k] = e;
        lmax = fmaxf(lmax, e);
    }
#pragma unroll
    for (int o = 32; o; o >>= 1) lmax = fmaxf(lmax, __shfl_down(lmax, o));
    if ((tid & 63) == 0) reds[tid >> 6] = lmax;
    __syncthreads();
    if (tid == 0) fb = fmaxf(fmaxf(reds[0], reds[1]), fmaxf(reds[2], reds[3]));
    __syncthreads();
    const float m = fb;

    float lsum = 0.f;
    for (int k = tid; k < nnz; k += NT) {
        float p = expf(sp[k] - m);
        sp[k] = p;
        lsum += p;
    }
#pragma unroll
    for (int o = 32; o; o >>= 1) lsum += __shfl_down(lsum, o);
    if ((tid & 63) == 0) reds[tid >> 6] = lsum;
    __syncthreads();
    if (tid == 0) fb = reds[0] + reds[1] + reds[2] + reds[3];
    __syncthreads();
    const float inv = 1.0f / fb;

    const int g = tid >> 6, lane = tid & 63;
    float ax = 0.f, ay = 0.f;
    for (int k = g; k < nnz; k += 4) {
        float pj = sp[k];
        unsigned hv = *(const unsigned*)&h2b[(size_t)scol[k] * 128 + lane * 2];
        ax += pj * __builtin_bit_cast(float, hv << 16);
        ay += pj * __builtin_bit_cast(float, hv & 0xffff0000u);
    }
    part[tid] = make_float2(ax, ay);
    __syncthreads();
    if (tid < 64) {
        float2 r0 = part[tid], r1 = part[tid + 64], r2 = part[tid + 128], r3 = part[tid + 192];
        float vx = (r0.x + r1.x + r2.x + r3.x) * inv;
        float vy = (r0.y + r1.y + r2.y + r3.y) * inv;
        out[(size_t)i * 128 + tid * 2]     = vx > 0.f ? vx : expm1f(vx);
        out[(size_t)i * 128 + tid * 2 + 1] = vy > 0.f ? vy : expm1f(vy);
    }
}

// ---------------------------------------------------------------------------
// z = h / max(||h||,1e-12); also writes bf16 copy zb
// ---------------------------------------------------------------------------
__global__ __launch_bounds__(256) void norm_kernel(const float* __restrict__ h,
                                                   float* __restrict__ z,
                                                   ushort_t* __restrict__ zb)
{
    const int row = (blockIdx.x * 256 + threadIdx.x) >> 6;
    const int lane = threadIdx.x & 63;
    if (row >= NNODES) return;
    const float* hr = h + (size_t)row * 128;
    float v0 = hr[lane], v1 = hr[lane + 64];
    float ss = v0 * v0 + v1 * v1;
#pragma unroll
    for (int o = 32; o; o >>= 1) ss += __shfl_down(ss, o);
    ss = __shfl(ss, 0);
    float invn = 1.0f / fmaxf(sqrtf(ss), 1e-12f);
    float z0 = v0 * invn, z1 = v1 * invn;
    z[(size_t)row * 128 + lane]      = z0;
    z[(size_t)row * 128 + lane + 64] = z1;
    zb[(size_t)row * 128 + lane]      = f2bf(z0);
    zb[(size_t)row * 128 + lane + 64] = f2bf(z1);
}

// ---------------------------------------------------------------------------
// Fallback dense attention (round-1 path) — only if ws is too small.
// ---------------------------------------------------------------------------
template <int D>
__global__ __launch_bounds__(256) void attn_kernel(const float* __restrict__ adj,
                                                   const float* __restrict__ Mm,
                                                   const float* __restrict__ sv,
                                                   const float* __restrict__ nv,
                                                   const float* __restrict__ h,
                                                   float* __restrict__ out)
{
    constexpr int NT = 256;
    constexpr int DCAP = 2048;
    __shared__ float pbuf[NNODES];
    __shared__ int   idxb[DCAP];
    __shared__ int   cnts[NT];
    __shared__ float reds[4];
    __shared__ float fbcast;
    __shared__ int   totc;

    const int tid = threadIdx.x;
    const int i = blockIdx.x;
    const size_t rowoff = (size_t)i * NNODES;
    const float si = sv[i];

    float lmax = -3.0e38f;
    for (int j = tid; j < NNODES; j += NT) {
        float a = adj[rowoff + j];
        float val = -9.0e15f;
        if (a > 0.f) {
            float e = (si + nv[j]) * Mm[rowoff + j];
            val = e > 0.f ? e : 0.2f * e;
            lmax = fmaxf(lmax, val);
        }
        pbuf[j] = val;
    }
#pragma unroll
    for (int o = 32; o; o >>= 1) lmax = fmaxf(lmax, __shfl_down(lmax, o));
    if ((tid & 63) == 0) reds[tid >> 6] = lmax;
    __syncthreads();
    if (tid == 0) fbcast = fmaxf(fmaxf(reds[0], reds[1]), fmaxf(reds[2], reds[3]));
    __syncthreads();
    const float m = fbcast;

    float lsum = 0.f;
    int myc = 0;
    for (int j = tid; j < NNODES; j += NT) {
        float v = pbuf[j];
        float p = (v > -8.9e15f) ? expf(v - m) : 0.f;
        pbuf[j] = p;
        lsum += p;
        if (p > 0.f) myc++;
    }
#pragma unroll
    for (int o = 32; o; o >>= 1) lsum += __shfl_down(lsum, o);
    if ((tid & 63) == 0) reds[tid >> 6] = lsum;
    cnts[tid] = myc;
    __syncthreads();
    if (tid == 0) {
        fbcast = reds[0] + reds[1] + reds[2] + reds[3];
        int run = 0;
        for (int t = 0; t < NT; ++t) { int c = cnts[t]; cnts[t] = run; run += c; }
        totc = run;
    }
    __syncthreads();
    const float inv = 1.0f / fbcast;
    const int nnz = totc;

    if (nnz <= DCAP) {
        int off = cnts[tid];
        for (int j = tid; j < NNODES; j += NT)
            if (pbuf[j] > 0.f) idxb[off++] = j;
    }
    __syncthreads();

    if constexpr (D == 512) {
        const int c = tid;
        float acc0 = 0.f, acc1 = 0.f;
        if (nnz <= DCAP) {
#pragma unroll 4
            for (int t = 0; t < nnz; ++t) {
                int j = idxb[t];
                float pj = pbuf[j];
                const float* hr = h + (size_t)j * 512;
                acc0 += pj * hr[c];
                acc1 += pj * hr[c + 256];
            }
        } else {
            for (int j = 0; j < NNODES; ++j) {
                float pj = pbuf[j];
                if (pj > 0.f) {
                    const float* hr = h + (size_t)j * 512;
                    acc0 += pj * hr[c];
                    acc1 += pj * hr[c + 256];
                }
            }
        }
        float r0 = acc0 * inv, r1 = acc1 * inv;
        out[(size_t)i * 512 + c]       = r0 > 0.f ? r0 : expm1f(r0);
        out[(size_t)i * 512 + c + 256] = r1 > 0.f ? r1 : expm1f(r1);
    } else {
        const int half = tid >> 7;
        const int c = tid & 127;
        float acc = 0.f;
        if (nnz <= DCAP) {
#pragma unroll 4
            for (int t = half; t < nnz; t += 2) {
                int j = idxb[t];
                acc += pbuf[j] * h[(size_t)j * 128 + c];
            }
        } else {
            for (int j = half; j < NNODES; j += 2) {
                float pj = pbuf[j];
                if (pj > 0.f) acc += pj * h[(size_t)j * 128 + c];
            }
        }
        __syncthreads();
        pbuf[tid] = acc;
        __syncthreads();
        if (tid < 128) {
            float r = (pbuf[tid] + pbuf[tid + 128]) * inv;
            out[(size_t)i * 128 + tid] = r > 0.f ? r : expm1f(r);
        }
    }
}

// ---------------------------------------------------------------------------
// f32 apred fallback
// ---------------------------------------------------------------------------
__global__ __launch_bounds__(256) void apred_kernel(const float* __restrict__ z,
                                                    float* __restrict__ out)
{
    __shared__ float sA[32][68];
    __shared__ float sB[32][68];

    const int tid = threadIdx.x;
    const int tx = tid & 15, ty = tid >> 4;
    const int bm = blockIdx.x * 64, bn = blockIdx.y * 64;

    float acc[4][4] = {};

    for (int k0 = 0; k0 < 128; k0 += 32) {
        for (int l = tid; l < 64 * 32; l += 256) {
            int r = l >> 5, kk = l & 31;
            sA[kk][r] = z[(size_t)(bm + r) * 128 + k0 + kk];
            sB[kk][r] = z[(size_t)(bn + r) * 128 + k0 + kk];
        }
        __syncthreads();
#pragma unroll
        for (int kk = 0; kk < 32; ++kk) {
            float a[4], b[4];
#pragma unroll
            for (int i = 0; i < 4; ++i) a[i] = sA[kk][ty * 4 + i];
#pragma unroll
            for (int j = 0; j < 4; ++j) b[j] = sB[kk][tx * 4 + j];
#pragma unroll
            for (int i = 0; i < 4; ++i)
#pragma unroll
                for (int j = 0; j < 4; ++j) acc[i][j] += a[i] * b[j];
        }
        __syncthreads();
    }

#pragma unroll
    for (int i = 0; i < 4; ++i) {
        float4 v;
        v.x = 1.0f / (1.0f + expf(-acc[i][0]));
        v.y = 1.0f / (1.0f + expf(-acc[i][1]));
        v.z = 1.0f / (1.0f + expf(-acc[i][2]));
        v.w = 1.0f / (1.0f + expf(-acc[i][3]));
        *(float4*)&out[(size_t)(bm + ty * 4 + i) * NNODES + bn + tx * 4] = v;
    }
}

// ---------------------------------------------------------------------------
extern "C" void kernel_launch(void* const* d_in, const int* in_sizes, int n_in,
                              void* d_out, int out_size, void* d_ws, size_t ws_size,
                              hipStream_t stream)
{
    const float* x   = (const float*)d_in[0];
    const float* adj = (const float*)d_in[1];
    const float* Mm  = (const float*)d_in[2];
    const float* W1  = (const float*)d_in[3];
    const float* as1 = (const float*)d_in[4];
    const float* an1 = (const float*)d_in[5];
    const float* W2  = (const float*)d_in[6];
    const float* as2 = (const float*)d_in[7];
    const float* an2 = (const float*)d_in[8];

    float* out   = (float*)d_out;
    float* Apred = out;
    float* z     = out + (size_t)NNODES * NNODES;

    // Scratch inside the Apred output region (dead until decoder):
    ushort_t* P   = (ushort_t*)Apred;                                  // 128 MiB
    ushort_t* hbT = (ushort_t*)((char*)Apred + (size_t)134217728);     // 8 MiB

    // ws layout
    float* ws  = (float*)d_ws;
    float* h1  = ws;                                  // 8192*512 f32 (reused as h2)
    float* h1p = h1 + (size_t)NNODES * 512;           // 8192*512 f32
    float* h2p = h1p + (size_t)NNODES * 512;          // 8192*128 f32
    float* sv  = h2p + (size_t)NNODES * 128;
    float* nv  = sv + NNODES;
    float* vals = nv + NNODES;                        // 8192*CAP f32
    unsigned short* cols = (unsigned short*)(vals + (size_t)NNODES * CAP);
    int* nnzs = (int*)(cols + (size_t)NNODES * CAP);
    ushort_t* zb  = (ushort_t*)(nnzs + NNODES);       // 8192*128 bf16
    ushort_t* h2b = zb + (size_t)NNODES * 128;        // 8192*128 bf16
    ushort_t* xb  = h2b + (size_t)NNODES * 128;       // 8192*512 bf16
    ushort_t* W1T = xb + (size_t)NNODES * 512;        // 512*512 bf16

    const size_t need = (size_t)((char*)(W1T + 512 * 512) - (char*)d_ws);

    if (ws_size >= need) {
        build_csr<<<dim3(2048), 256, 0, stream>>>(adj, Mm, cols, vals, nnzs);

        // layer 1: h1 = x @ W1 (bf16 MFMA)
        cast_bf<<<dim3(4096), 256, 0, stream>>>(x, xb, NNODES * 512 / 4);
        tcast<<<dim3(8, 8), 256, 0, stream>>>(W1, W1T, 512, 512);
        gemm_mfma<0><<<dim3(64, 4), 256, 0, stream>>>(xb, W1T, h1, 512, 512);
        sn_kernel<512><<<dim3(2048), 256, 0, stream>>>(h1, as1, an1, sv, nv);
        softmax_dense<<<dim3(NNODES), 256, 0, stream>>>(cols, vals, nnzs, sv, nv, P);
        tcast<<<dim3(128, 8), 256, 0, stream>>>(h1, hbT, NNODES, 512);
        gemm_mfma<1><<<dim3(64, 4), 256, 0, stream>>>(P, hbT, h1p, 512, NNODES);

        // layer 2 (f32 gemm protects the z path)
        gemm64<<<dim3(128, 2), 256, 0, stream>>>(h1p, W2, h1, NNODES, 128, 512);
        sn_kernel<128><<<dim3(2048), 256, 0, stream>>>(h1, as2, an2, sv, nv);
        cast_bf<<<dim3(1024), 256, 0, stream>>>(h1, h2b, NNODES * 128 / 4);
        attn2_csr<<<dim3(NNODES), 256, 0, stream>>>(cols, vals, nnzs, sv, nv, h2b, h2p);

        // decoder
        norm_kernel<<<dim3(2048), 256, 0, stream>>>(h2p, z, zb);
        apred_mfma<<<dim3(64, 64), 256, 0, stream>>>(zb, Apred);
    } else {
        // fallback: round-1 dense f32 path
        gemm64<<<dim3(128, 8), 256, 0, stream>>>((const float*)d_in[0], W1, h1, NNODES, 512, 512);
        sn_kernel<512><<<dim3(2048), 256, 0, stream>>>(h1, as1, an1, sv, nv);
        attn_kernel<512><<<dim3(NNODES), 256, 0, stream>>>(adj, Mm, sv, nv, h1, h1p);

        gemm64<<<dim3(128, 2), 256, 0, stream>>>(h1p, W2, h1, NNODES, 128, 512);
        sn_kernel<128><<<dim3(2048), 256, 0, stream>>>(h1, as2, an2, sv, nv);
        attn_kernel<128><<<dim3(NNODES), 256, 0, stream>>>(adj, Mm, sv, nv, h1, h2p);

        norm_kernel<<<dim3(2048), 256, 0, stream>>>(h2p, z, zb);
        apred_kernel<<<dim3(128, 128), 256, 0, stream>>>(z, Apred);
    }
}